// Round 1
// baseline (1587.437 us; speedup 1.0000x reference)
//
#include <hip/hip_runtime.h>
#include <math.h>

#define CIN 512
#define COUT 256
#define TT 4
#define NN 8
#define HH 32
#define WW 32
#define FR (TT*NN)   /* 32 frames */
#define HW (HH*WW)   /* 1024 */
#define BN_EPS 1e-5

/* ---------------- kernel 1: BN1 per-channel stats (f64) ---------------- */
__global__ __launch_bounds__(256) void k_bn1_stats(const float* __restrict__ x,
                                                   const float* __restrict__ gamma1,
                                                   double* __restrict__ mean,
                                                   double* __restrict__ alpha) {
    int c = blockIdx.x;           // 0..511
    int tid = threadIdx.x;        // 0..255
    double s1 = 0.0, s2 = 0.0;
    const float4* x4 = reinterpret_cast<const float4*>(x);
    for (int f = 0; f < FR; ++f) {
        size_t base4 = ((size_t)(f * CIN + c) * HW) >> 2;
        float4 v = x4[base4 + tid];           // 256 thr * 4 = 1024 floats/frame
        s1 += (double)v.x + (double)v.y + (double)v.z + (double)v.w;
        s2 += (double)v.x * v.x + (double)v.y * v.y + (double)v.z * v.z + (double)v.w * v.w;
    }
    __shared__ double l1[256], l2[256];
    l1[tid] = s1; l2[tid] = s2;
    __syncthreads();
    for (int ofs = 128; ofs > 0; ofs >>= 1) {
        if (tid < ofs) { l1[tid] += l1[tid + ofs]; l2[tid] += l2[tid + ofs]; }
        __syncthreads();
    }
    if (tid == 0) {
        double n = (double)(FR * HW);
        double m = l1[0] / n;
        double var = l2[0] / n - m * m;
        mean[c] = m;
        alpha[c] = (double)gamma1[c] / sqrt(var + BN_EPS);
    }
}

/* ---------------- kernel 2a: folded conv weights w2t[c][o] (f64) ---------------- */
__global__ void k_fold_w(const float* __restrict__ conv_w,
                         const double* __restrict__ alpha,
                         double* __restrict__ w2t) {
    int c = blockIdx.x, o = threadIdx.x;
    w2t[(size_t)c * COUT + o] = (double)conv_w[(size_t)o * CIN + c] * alpha[c];
}

/* ---------------- kernel 2b: folded bias[o] (f64) ---------------- */
__global__ void k_fold_bias(const float* __restrict__ conv_w,
                            const float* __restrict__ beta1,
                            const double* __restrict__ mean,
                            const double* __restrict__ alpha,
                            double* __restrict__ bias) {
    int o = threadIdx.x;
    double s = 0.0;
    for (int c = 0; c < CIN; ++c)
        s += ((double)beta1[c] - mean[c] * alpha[c]) * (double)conv_w[(size_t)o * CIN + c];
    bias[o] = s;
}

/* ---------------- kernel 3: f64 GEMM (1x1 conv) + LIF + spike count ----------------
   block = one (n,y,x0..x0+3) tile, 256 threads = o. */
__global__ __launch_bounds__(256) void k_gemm_lif(const float* __restrict__ x,
                                                  const double* __restrict__ w2t,
                                                  const double* __restrict__ bias,
                                                  const float* __restrict__ lif_w,
                                                  float* __restrict__ spk,
                                                  int* __restrict__ cnt) {
    int blk = blockIdx.x;            // 0..2047
    int n = blk >> 8;
    int y = (blk >> 3) & 31;
    int x0 = (blk & 7) << 2;
    int o = threadIdx.x;
    __shared__ float xs[TT][CIN][4];
    for (int k = 0; k < 32; ++k) {
        int f = threadIdx.x + (k << 8);      // 0..8191
        int t = f >> 11;
        int c = (f >> 2) & 511;
        int m = f & 3;
        xs[t][c][m] = x[(size_t)((t * NN + n) * CIN + c) * HW + y * WW + x0 + m];
    }
    __syncthreads();

    double acc[TT][4];
#pragma unroll
    for (int t = 0; t < TT; ++t)
#pragma unroll
        for (int m = 0; m < 4; ++m) acc[t][m] = 0.0;

    for (int c = 0; c < CIN; ++c) {
        double w = w2t[(size_t)c * COUT + o];
#pragma unroll
        for (int t = 0; t < TT; ++t) {
            float4 v = *reinterpret_cast<const float4*>(&xs[t][c][0]);
            acc[t][0] += (double)v.x * w;
            acc[t][1] += (double)v.y * w;
            acc[t][2] += (double)v.z * w;
            acc[t][3] += (double)v.w * w;
        }
    }

    double wl = (double)lif_w[0];
    double tau = 1.0 / (1.0 + exp(-wl));     // sigmoid
    double b = bias[o];
    int count = 0;
    double v[4] = {0.0, 0.0, 0.0, 0.0};
#pragma unroll
    for (int t = 0; t < TT; ++t) {
#pragma unroll
        for (int m = 0; m < 4; ++m) {
            double h = b + acc[t][m];
            double vv = v[m] + (h - v[m]) * tau;
            bool s = (vv >= 1.0);            // heaviside(v-1)
            spk[(size_t)((t * NN + n) * COUT + o) * HW + y * WW + x0 + m] = s ? 1.0f : 0.0f;
            count += s ? 1 : 0;
            v[m] = s ? 0.0 : vv;             // hard reset
        }
    }
    atomicAdd(&cnt[o], count);
}

/* ---------------- kernel 4pre: BN2 affine from spike counts ---------------- */
__global__ void k_bn2_prep(const int* __restrict__ cnt,
                           const float* __restrict__ gamma2,
                           const float* __restrict__ beta2,
                           double* __restrict__ a2, double* __restrict__ b2) {
    int c = threadIdx.x;
    double n = (double)(FR * 67 * 67);       // 143648
    double m = (double)cnt[c] / n;
    double var = m - m * m;                  // binary values
    double a = (double)gamma2[c] / sqrt(var + BN_EPS);
    a2[c] = a;
    b2[c] = (double)beta2[c] - m * a;
}

/* ---------------- kernel 4a: scaled transposed weight table WA[c][i][o][j0..3] ---------------- */
__global__ __launch_bounds__(256) void k_make_wa(const float* __restrict__ up_w,
                                                 const double* __restrict__ a2,
                                                 float4* __restrict__ wa) {
    int c = blockIdx.x, o = threadIdx.x;
    double a = a2[c];
    const float4* u4 = reinterpret_cast<const float4*>(up_w + ((size_t)c * COUT + o) * 16);
#pragma unroll
    for (int i = 0; i < 4; ++i) {
        float4 q = u4[i];
        float4 r;
        r.x = (float)(a * (double)q.x);
        r.y = (float)(a * (double)q.y);
        r.z = (float)(a * (double)q.z);
        r.w = (float)(a * (double)q.w);
        wa[(size_t)(c * 4 + i) * COUT + o] = r;
    }
}

/* ---------------- kernel 4b: uniform constant K[o] ---------------- */
__global__ void k_kconst(const float* __restrict__ up_w,
                         const double* __restrict__ b2,
                         float* __restrict__ kc) {
    int o = threadIdx.x;
    double s = 0.0;
    for (int c = 0; c < COUT; ++c) {
        const float* u = up_w + ((size_t)c * COUT + o) * 16;
        double t = 0.0;
#pragma unroll
        for (int k = 0; k < 16; ++k) t += (double)u[k];
        s += b2[c] * t;
    }
    kc[o] = (float)s;
}

/* ---------------- kernel 5: 4-tap sparse-input conv (transposed conv) ----------------
   block = (frame b, out row y); 256 threads = o; each thread computes 64 x. */
__global__ __launch_bounds__(256) void k_deconv(const float* __restrict__ spk,
                                                const float4* __restrict__ wa,
                                                const float* __restrict__ kc,
                                                float* __restrict__ out) {
    int b = blockIdx.x >> 6;
    int y = blockIdx.x & 63;
    int o = threadIdx.x;
    int py = y & 1;
    int ybase = ((y + py) >> 1) - 1;

    __shared__ float rows[128 * 2 * 36];     // [c_local][dy][36], 36 KB, 2 c-chunks

    float acc[64];
#pragma unroll
    for (int i = 0; i < 64; ++i) acc[i] = 0.0f;

    for (int cc = 0; cc < 2; ++cc) {
        int c0 = cc * 128;
        __syncthreads();                     // protect previous chunk
        for (int i = threadIdx.x; i < 128 * 2 * 36; i += 256) rows[i] = 0.0f;
        __syncthreads();
        for (int idx = threadIdx.x; idx < 128 * 2 * 32; idx += 256) {
            int cl = idx >> 6;
            int dy = (idx >> 5) & 1;
            int sx = idx & 31;
            int sy = ybase + dy;
            if (sy >= 0 && sy < 32) {
                rows[(cl * 2 + dy) * 36 + sx + 1] =
                    spk[(size_t)(b * COUT + c0 + cl) * HW + sy * WW + sx];
            }
        }
        __syncthreads();

        for (int cl = 0; cl < 128; ++cl) {
#pragma unroll
            for (int dy = 0; dy < 2; ++dy) {
                int i = 3 - py - 2 * dy;     // original up_w row index
                float4 W = wa[(size_t)((c0 + cl) * 4 + i) * COUT + o];
                const float4* r4 = reinterpret_cast<const float4*>(rows + (cl * 2 + dy) * 36);
                float4 Q0 = r4[0];
#pragma unroll
                for (int g = 0; g < 8; ++g) {
                    float4 Q1 = r4[g + 1];
                    float e0 = Q0.x, e1 = Q0.y, e2 = Q0.z, e3 = Q0.w;
                    float e4 = Q1.x, e5 = Q1.y;
                    acc[8 * g + 0] += e0 * W.w + e1 * W.y;
                    acc[8 * g + 1] += e1 * W.z + e2 * W.x;
                    acc[8 * g + 2] += e1 * W.w + e2 * W.y;
                    acc[8 * g + 3] += e2 * W.z + e3 * W.x;
                    acc[8 * g + 4] += e2 * W.w + e3 * W.y;
                    acc[8 * g + 5] += e3 * W.z + e4 * W.x;
                    acc[8 * g + 6] += e3 * W.w + e4 * W.y;
                    acc[8 * g + 7] += e4 * W.z + e5 * W.x;
                    Q0 = Q1;
                }
            }
        }
    }

    float base = kc[o];
    size_t ob = ((size_t)(b * COUT + o) * 64 + y) * 64;
#pragma unroll
    for (int i = 0; i < 16; ++i) {
        float4 r;
        r.x = base + acc[4 * i + 0];
        r.y = base + acc[4 * i + 1];
        r.z = base + acc[4 * i + 2];
        r.w = base + acc[4 * i + 3];
        *reinterpret_cast<float4*>(out + ob + 4 * i) = r;
    }
}

/* ---------------- host launcher ---------------- */
extern "C" void kernel_launch(void* const* d_in, const int* in_sizes, int n_in,
                              void* d_out, int out_size, void* d_ws, size_t ws_size,
                              hipStream_t stream) {
    (void)in_sizes; (void)n_in; (void)out_size; (void)ws_size;
    const float* x        = (const float*)d_in[0];
    const float* bn1_g    = (const float*)d_in[1];
    const float* bn1_b    = (const float*)d_in[2];
    const float* conv_w   = (const float*)d_in[3];
    const float* lif_w    = (const float*)d_in[4];
    const float* bn2_g    = (const float*)d_in[5];
    const float* bn2_b    = (const float*)d_in[6];
    const float* up_w     = (const float*)d_in[7];
    float* out = (float*)d_out;

    char* ws = (char*)d_ws;
    // workspace layout (all offsets 1 KiB-aligned)
    float*  spk   = (float*) (ws + 0);                       // 33,554,432 B
    double* mean  = (double*)(ws + 33554432);                // 4 KB
    double* alpha = (double*)(ws + 33558528);                // 4 KB
    double* w2t   = (double*)(ws + 33562624);                // 1 MB
    double* bias  = (double*)(ws + 34611200);                // 2 KB
    double* a2    = (double*)(ws + 34613248);                // 2 KB
    double* b2    = (double*)(ws + 34615296);                // 2 KB
    int*    cnt   = (int*)   (ws + 34617344);                // 1 KB
    float*  kc    = (float*) (ws + 34618368);                // 1 KB
    float4* wa    = (float4*)(ws + 34619392);                // 4 MB

    hipMemsetAsync(cnt, 0, COUT * sizeof(int), stream);

    k_bn1_stats<<<CIN, 256, 0, stream>>>(x, bn1_g, mean, alpha);
    k_fold_w<<<CIN, COUT, 0, stream>>>(conv_w, alpha, w2t);
    k_fold_bias<<<1, COUT, 0, stream>>>(conv_w, bn1_b, mean, alpha, bias);
    k_gemm_lif<<<2048, 256, 0, stream>>>(x, w2t, bias, lif_w, spk, cnt);
    k_bn2_prep<<<1, COUT, 0, stream>>>(cnt, bn2_g, bn2_b, a2, b2);
    k_make_wa<<<COUT, COUT, 0, stream>>>(up_w, a2, wa);
    k_kconst<<<1, COUT, 0, stream>>>(up_w, b2, kc);
    k_deconv<<<32 * 64, 256, 0, stream>>>(spk, wa, kc, out);
}

// Round 2
// 618.170 us; speedup vs baseline: 2.5680x; 2.5680x over previous
//
#include <hip/hip_runtime.h>
#include <math.h>

#define CIN 512
#define COUT 256
#define TT 4
#define NN 8
#define HH 32
#define WW 32
#define FR (TT*NN)   /* 32 frames */
#define HW (HH*WW)   /* 1024 */
#define BN_EPS 1e-5

typedef unsigned short ushort_t;
typedef unsigned int uint_t;
typedef __attribute__((ext_vector_type(8))) short short8;
typedef __attribute__((ext_vector_type(4))) float f32x4;

__device__ inline ushort_t f2bf(float f) {
    unsigned int u = __float_as_uint(f);
    unsigned int r = u + 0x7FFFu + ((u >> 16) & 1u);
    return (ushort_t)(r >> 16);
}

/* ---------------- kernel 1: BN1 per-channel stats (f64) ---------------- */
__global__ __launch_bounds__(256) void k_bn1_stats(const float* __restrict__ x,
                                                   const float* __restrict__ gamma1,
                                                   double* __restrict__ mean,
                                                   double* __restrict__ alpha) {
    int c = blockIdx.x;           // 0..511
    int tid = threadIdx.x;        // 0..255
    double s1 = 0.0, s2 = 0.0;
    const float4* x4 = reinterpret_cast<const float4*>(x);
    for (int f = 0; f < FR; ++f) {
        size_t base4 = ((size_t)(f * CIN + c) * HW) >> 2;
        float4 v = x4[base4 + tid];
        s1 += (double)v.x + (double)v.y + (double)v.z + (double)v.w;
        s2 += (double)v.x * v.x + (double)v.y * v.y + (double)v.z * v.z + (double)v.w * v.w;
    }
    __shared__ double l1[256], l2[256];
    l1[tid] = s1; l2[tid] = s2;
    __syncthreads();
    for (int ofs = 128; ofs > 0; ofs >>= 1) {
        if (tid < ofs) { l1[tid] += l1[tid + ofs]; l2[tid] += l2[tid + ofs]; }
        __syncthreads();
    }
    if (tid == 0) {
        double n = (double)(FR * HW);
        double m = l1[0] / n;
        double var = l2[0] / n - m * m;
        mean[c] = m;
        alpha[c] = (double)gamma1[c] / sqrt(var + BN_EPS);
    }
}

/* ---------------- kernel 2a: folded conv weights w2t[c][o] (f64) ---------------- */
__global__ void k_fold_w(const float* __restrict__ conv_w,
                         const double* __restrict__ alpha,
                         double* __restrict__ w2t) {
    int c = blockIdx.x, o = threadIdx.x;
    w2t[(size_t)c * COUT + o] = (double)conv_w[(size_t)o * CIN + c] * alpha[c];
}

/* ---------------- kernel 2b: folded bias[o] (f64) ---------------- */
__global__ void k_fold_bias(const float* __restrict__ conv_w,
                            const float* __restrict__ beta1,
                            const double* __restrict__ mean,
                            const double* __restrict__ alpha,
                            double* __restrict__ bias) {
    int o = threadIdx.x;
    double s = 0.0;
    for (int c = 0; c < CIN; ++c)
        s += ((double)beta1[c] - mean[c] * alpha[c]) * (double)conv_w[(size_t)o * CIN + c];
    bias[o] = s;
}

/* ---------------- kernel 3: f64 GEMM (1x1 conv) + LIF + spike count ----------------
   block = one (n,y,x0..x0+3) tile, 256 threads = o.
   Spikes written channel-last bf16: spk[b][sy][sx][c]. */
__global__ __launch_bounds__(256) void k_gemm_lif(const float* __restrict__ x,
                                                  const double* __restrict__ w2t,
                                                  const double* __restrict__ bias,
                                                  const float* __restrict__ lif_w,
                                                  ushort_t* __restrict__ spk,
                                                  int* __restrict__ cnt) {
    int blk = blockIdx.x;            // 0..2047
    int n = blk >> 8;
    int y = (blk >> 3) & 31;
    int x0 = (blk & 7) << 2;
    int o = threadIdx.x;
    __shared__ float xs[TT][CIN][4];
    for (int k = 0; k < 32; ++k) {
        int f = threadIdx.x + (k << 8);
        int t = f >> 11;
        int c = (f >> 2) & 511;
        int m = f & 3;
        xs[t][c][m] = x[(size_t)((t * NN + n) * CIN + c) * HW + y * WW + x0 + m];
    }
    __syncthreads();

    double acc[TT][4];
#pragma unroll
    for (int t = 0; t < TT; ++t)
#pragma unroll
        for (int m = 0; m < 4; ++m) acc[t][m] = 0.0;

    for (int c = 0; c < CIN; ++c) {
        double w = w2t[(size_t)c * COUT + o];
#pragma unroll
        for (int t = 0; t < TT; ++t) {
            float4 v = *reinterpret_cast<const float4*>(&xs[t][c][0]);
            acc[t][0] += (double)v.x * w;
            acc[t][1] += (double)v.y * w;
            acc[t][2] += (double)v.z * w;
            acc[t][3] += (double)v.w * w;
        }
    }

    double wl = (double)lif_w[0];
    double tau = 1.0 / (1.0 + exp(-wl));
    double b = bias[o];
    int count = 0;
    double v[4] = {0.0, 0.0, 0.0, 0.0};
#pragma unroll
    for (int t = 0; t < TT; ++t) {
#pragma unroll
        for (int m = 0; m < 4; ++m) {
            double h = b + acc[t][m];
            double vv = v[m] + (h - v[m]) * tau;
            bool s = (vv >= 1.0);
            spk[((size_t)(t * NN + n) * HW + y * WW + x0 + m) * COUT + o] =
                s ? (ushort_t)0x3F80 : (ushort_t)0;
            count += s ? 1 : 0;
            v[m] = s ? 0.0 : vv;
        }
    }
    atomicAdd(&cnt[o], count);
}

/* ---------------- kernel 4pre: BN2 affine from spike counts ---------------- */
__global__ void k_bn2_prep(const int* __restrict__ cnt,
                           const float* __restrict__ gamma2,
                           const float* __restrict__ beta2,
                           double* __restrict__ a2, double* __restrict__ b2) {
    int c = threadIdx.x;
    double n = (double)(FR * 67 * 67);
    double m = (double)cnt[c] / n;
    double var = m - m * m;
    double a = (double)gamma2[c] / sqrt(var + BN_EPS);
    a2[c] = a;
    b2[c] = (double)beta2[c] - m * a;
}

/* ---------------- kernel 4a: bf16 weight table Wt[i][j][o][c] ---------------- */
__global__ __launch_bounds__(256) void k_wt_prep(const float* __restrict__ up_w,
                                                 const double* __restrict__ a2,
                                                 ushort_t* __restrict__ Wt) {
    int c = blockIdx.x, o = threadIdx.x;
    double a = a2[c];
    const float* u = up_w + ((size_t)c * COUT + o) * 16;
#pragma unroll
    for (int ij = 0; ij < 16; ++ij) {
        float w = (float)(a * (double)u[ij]);
        Wt[((size_t)ij << 16) + (o << 8) + c] = f2bf(w);
    }
}

/* ---------------- kernel 4b: uniform constant K[o] ---------------- */
__global__ void k_kconst(const float* __restrict__ up_w,
                         const double* __restrict__ b2,
                         float* __restrict__ kc) {
    int o = threadIdx.x;
    double s = 0.0;
    for (int c = 0; c < COUT; ++c) {
        const float* u = up_w + ((size_t)c * COUT + o) * 16;
        double t = 0.0;
#pragma unroll
        for (int k = 0; k < 16; ++k) t += (double)u[k];
        s += b2[c] * t;
    }
    kc[o] = (float)s;
}

/* ---------------- kernel 5: MFMA implicit-GEMM transposed conv ----------------
   block = (frame b, row parity py, quarter-row pair Y0). 512 thr = 8 waves.
   wave = (px = w>>2, o-group og = w&3, 64 o each).
   GEMM: D[o][pixel] = sum_{c,tap} Wt[i][j][o][c] * S[c][shifted pixel].
   A = weights (M=o, K=c), B = spikes from LDS slab (K=c, N=pixel). */
__global__ __launch_bounds__(512) void k_deconv_mfma(const ushort_t* __restrict__ spk,
                                                     const ushort_t* __restrict__ Wt,
                                                     const float* __restrict__ kc,
                                                     float* __restrict__ out) {
    int blk = blockIdx.x;
    int b  = blk >> 5;
    int py = (blk >> 4) & 1;
    int Yb = (blk & 15) << 1;
    int tid = threadIdx.x;
    int wv  = tid >> 6;
    int lane = tid & 63;
    int px = wv >> 2;
    int og = wv & 3;
    int lr = lane & 15;
    int kq = lane >> 4;

    __shared__ ushort_t slab[3 * 34 * 256];     // 52224 B, XOR-swizzled

    /* stage spike slab: rows sy = Yb-1+py+r (r=0..2), cols sx = xc-1 (xc=0..33) */
    int sb = Yb - 1 + py;
    for (int q = tid; q < 3 * 34 * 32; q += 512) {
        int pix = q >> 5;          // 0..101
        int l = q & 31;            // 16B chunk within 512B pixel row
        int r = pix / 34;
        int xc = pix - r * 34;
        int sy = sb + r;
        int sx = xc - 1;
        uint_t off = ((uint_t)(pix << 9) + (uint_t)(l << 4)) ^ ((uint_t)(xc & 7) << 4);
        uint4* dst = (uint4*)((char*)slab + off);
        if (sy >= 0 && sy < 32 && sx >= 0 && sx < 32) {
            *dst = *(const uint4*)(spk + ((size_t)b * HW + sy * 32 + sx) * COUT + l * 8);
        } else {
            *dst = make_uint4(0u, 0u, 0u, 0u);
        }
    }
    __syncthreads();

    f32x4 acc[4][4];
#pragma unroll
    for (int pf = 0; pf < 4; ++pf)
#pragma unroll
        for (int of = 0; of < 4; ++of)
            acc[pf][of] = (f32x4){0.f, 0.f, 0.f, 0.f};

    int obase = og << 6;

#pragma unroll
    for (int dy = 0; dy < 2; ++dy) {
#pragma unroll
        for (int dx = 0; dx < 2; ++dx) {
            int i = 3 - py - 2 * dy;
            int j = 3 - px - 2 * dx;
            const ushort_t* wp = Wt + ((size_t)(i * 4 + j) << 16)
                                    + ((uint_t)(obase + lr) << 8) + (kq << 3);
            uint_t sbase[4], swz[4];
#pragma unroll
            for (int pf = 0; pf < 4; ++pf) {
                int pid = pf * 16 + lr;
                int Yq = pid >> 5;
                int X  = pid & 31;
                int xc = X + dx + px;
                int prow = (Yq + dy) * 34 + xc;
                sbase[pf] = ((uint_t)prow << 9) + ((uint_t)kq << 4);
                swz[pf]   = ((uint_t)(xc & 7)) << 4;
            }
#pragma unroll
            for (int cs = 0; cs < 8; ++cs) {
                short8 aw[4];
#pragma unroll
                for (int of = 0; of < 4; ++of)
                    aw[of] = *(const short8*)(wp + of * 16 * 256 + cs * 32);
                short8 bs[4];
#pragma unroll
                for (int pf = 0; pf < 4; ++pf)
                    bs[pf] = *(const short8*)((const char*)slab +
                              ((sbase[pf] + ((uint_t)cs << 6)) ^ swz[pf]));
#pragma unroll
                for (int pf = 0; pf < 4; ++pf)
#pragma unroll
                    for (int of = 0; of < 4; ++of)
                        acc[pf][of] = __builtin_amdgcn_mfma_f32_16x16x32_bf16(
                            aw[of], bs[pf], acc[pf][of], 0, 0, 0);
            }
        }
    }

    /* epilogue: D col = lane&15 = pixel-local, row = kq*4+reg = o-local */
#pragma unroll
    for (int of = 0; of < 4; ++of) {
#pragma unroll
        for (int rg = 0; rg < 4; ++rg) {
            int o = obase + of * 16 + kq * 4 + rg;
            float base = kc[o];
#pragma unroll
            for (int pf = 0; pf < 4; ++pf) {
                int pid = pf * 16 + lr;
                int Yq = pid >> 5;
                int X  = pid & 31;
                int y = ((Yb + Yq) << 1) + py;
                int x = (X << 1) + px;
                out[((size_t)(b * COUT + o) << 12) + (y << 6) + x] = acc[pf][of][rg] + base;
            }
        }
    }
}

/* ---------------- host launcher ---------------- */
extern "C" void kernel_launch(void* const* d_in, const int* in_sizes, int n_in,
                              void* d_out, int out_size, void* d_ws, size_t ws_size,
                              hipStream_t stream) {
    (void)in_sizes; (void)n_in; (void)out_size; (void)ws_size;
    const float* x        = (const float*)d_in[0];
    const float* bn1_g    = (const float*)d_in[1];
    const float* bn1_b    = (const float*)d_in[2];
    const float* conv_w   = (const float*)d_in[3];
    const float* lif_w    = (const float*)d_in[4];
    const float* bn2_g    = (const float*)d_in[5];
    const float* bn2_b    = (const float*)d_in[6];
    const float* up_w     = (const float*)d_in[7];
    float* out = (float*)d_out;

    char* ws = (char*)d_ws;
    ushort_t* spk  = (ushort_t*)(ws + 0);            // 16,777,216 B (bf16 channel-last)
    double* mean   = (double*)(ws + 16777216);       // 4 KB
    double* alpha  = (double*)(ws + 16781312);       // 4 KB
    double* w2t    = (double*)(ws + 16785408);       // 1 MB
    double* bias   = (double*)(ws + 17833984);       // 2 KB
    double* a2     = (double*)(ws + 17836032);       // 2 KB
    double* b2     = (double*)(ws + 17838080);       // 2 KB
    int*    cnt    = (int*)   (ws + 17840128);       // 1 KB
    float*  kc     = (float*) (ws + 17841152);       // 1 KB
    ushort_t* Wt   = (ushort_t*)(ws + 17842176);     // 2 MB

    hipMemsetAsync(cnt, 0, COUT * sizeof(int), stream);

    k_bn1_stats<<<CIN, 256, 0, stream>>>(x, bn1_g, mean, alpha);
    k_fold_w<<<CIN, COUT, 0, stream>>>(conv_w, alpha, w2t);
    k_fold_bias<<<1, COUT, 0, stream>>>(conv_w, bn1_b, mean, alpha, bias);
    k_gemm_lif<<<2048, 256, 0, stream>>>(x, w2t, bias, lif_w, spk, cnt);
    k_bn2_prep<<<1, COUT, 0, stream>>>(cnt, bn2_g, bn2_b, a2, b2);
    k_wt_prep<<<COUT, COUT, 0, stream>>>(up_w, a2, Wt);
    k_kconst<<<1, COUT, 0, stream>>>(up_w, b2, kc);
    k_deconv_mfma<<<32 * 2 * 16, 512, 0, stream>>>(spk, Wt, kc, out);
}

// Round 3
// 550.653 us; speedup vs baseline: 2.8828x; 1.1226x over previous
//
#include <hip/hip_runtime.h>
#include <math.h>

#define CIN 512
#define COUT 256
#define TT 4
#define NN 8
#define HH 32
#define WW 32
#define FR (TT*NN)   /* 32 frames */
#define HW (HH*WW)   /* 1024 */
#define BN_EPS 1e-5
#define FLAGCAP (1<<20)

typedef unsigned short ushort_t;
typedef unsigned int uint_t;
typedef __attribute__((ext_vector_type(8))) short short8;
typedef __attribute__((ext_vector_type(4))) float f32x4;

__device__ inline ushort_t f2bf(float f) {
    uint_t u = __float_as_uint(f);
    uint_t r = u + 0x7FFFu + ((u >> 16) & 1u);
    return (ushort_t)(r >> 16);
}
__device__ inline float bf2f(ushort_t a) { return __uint_as_float(((uint_t)a) << 16); }

/* ---------------- kernel 1: BN1 per-channel stats (f64) ---------------- */
__global__ __launch_bounds__(256) void k_bn1_stats(const float* __restrict__ x,
                                                   const float* __restrict__ gamma1,
                                                   double* __restrict__ mean,
                                                   double* __restrict__ alpha) {
    int c = blockIdx.x;
    int tid = threadIdx.x;
    double s1 = 0.0, s2 = 0.0;
    const float4* x4 = reinterpret_cast<const float4*>(x);
    for (int f = 0; f < FR; ++f) {
        size_t base4 = ((size_t)(f * CIN + c) * HW) >> 2;
        float4 v = x4[base4 + tid];
        s1 += (double)v.x + (double)v.y + (double)v.z + (double)v.w;
        s2 += (double)v.x * v.x + (double)v.y * v.y + (double)v.z * v.z + (double)v.w * v.w;
    }
    __shared__ double l1[256], l2[256];
    l1[tid] = s1; l2[tid] = s2;
    __syncthreads();
    for (int ofs = 128; ofs > 0; ofs >>= 1) {
        if (tid < ofs) { l1[tid] += l1[tid + ofs]; l2[tid] += l2[tid + ofs]; }
        __syncthreads();
    }
    if (tid == 0) {
        double n = (double)(FR * HW);
        double m = l1[0] / n;
        double var = l2[0] / n - m * m;
        mean[c] = m;
        alpha[c] = (double)gamma1[c] / sqrt(var + BN_EPS);
    }
}

/* ---------------- kernel 2a: folded weights: f64 table + bf16 split tables ----------------
   Wa/Wb blocked layout: [(c>>3)][o][c&7] so B-operand lanes (consecutive o) read contiguous 16B. */
__global__ __launch_bounds__(256) void k_prep_wsplit(const float* __restrict__ conv_w,
                                                     const double* __restrict__ alpha,
                                                     double* __restrict__ w2t,
                                                     ushort_t* __restrict__ Wa,
                                                     ushort_t* __restrict__ Wb) {
    int o = blockIdx.x;
    for (int c = threadIdx.x; c < CIN; c += 256) {
        double w = (double)conv_w[(size_t)o * CIN + c] * alpha[c];
        w2t[(size_t)c * COUT + o] = w;
        float wf = (float)w;
        ushort_t a = f2bf(wf);
        ushort_t b = f2bf(wf - bf2f(a));
        size_t base = ((size_t)(c >> 3) * COUT + o) * 8 + (c & 7);
        Wa[base] = a; Wb[base] = b;
    }
}

/* ---------------- kernel 2b: folded bias[o] (f64) ---------------- */
__global__ void k_fold_bias(const float* __restrict__ conv_w,
                            const float* __restrict__ beta1,
                            const double* __restrict__ mean,
                            const double* __restrict__ alpha,
                            double* __restrict__ bias) {
    int o = threadIdx.x;
    double s = 0.0;
    for (int c = 0; c < CIN; ++c)
        s += ((double)beta1[c] - mean[c] * alpha[c]) * (double)conv_w[(size_t)o * CIN + c];
    bias[o] = s;
}

/* ---------------- kernel 3: split-bf16 MFMA GEMM + margin + LIF ----------------
   block: 16 spatials (n fixed, hw0..hw0+15) x 256 o. 4 waves: (pxhalf, ohalf).
   pixel-row index px = spatial_local*4 + t  ->  lane holds 4 t's in acc regs.
   3 product passes + 1 |wa|*|xa| margin pass, all f32-accumulated. */
__global__ __launch_bounds__(256) void k_gemm_lif_mfma(
    const float* __restrict__ x, const ushort_t* __restrict__ Wa,
    const ushort_t* __restrict__ Wb, const double* __restrict__ bias,
    const float* __restrict__ lif_w, ushort_t* __restrict__ spk,
    int* __restrict__ cnt, uint_t* __restrict__ flags, uint_t* __restrict__ flagcnt)
{
    int blk = blockIdx.x;            // 512 blocks
    int n   = blk >> 6;
    int hw0 = (blk & 63) << 4;
    int tid = threadIdx.x;
    int wv = tid >> 6, lane = tid & 63;
    int lr = lane & 15, kq = lane >> 4;
    int pxh = wv >> 1, oh = wv & 1;

    __shared__ ushort_t Xa[64 * 128];       // 16 KB, XOR-swizzled rows
    __shared__ ushort_t Xb[64 * 128];       // 16 KB
    __shared__ uint_t   cl[4 * 64 * 8];     // 8 KB spike-count scratch

    f32x4 acc[2][8], accS[2][8];
#pragma unroll
    for (int m = 0; m < 2; ++m)
#pragma unroll
        for (int ot = 0; ot < 8; ++ot) {
            acc[m][ot]  = (f32x4){0.f, 0.f, 0.f, 0.f};
            accS[m][ot] = (f32x4){0.f, 0.f, 0.f, 0.f};
        }

    const short8 MSK = {0x7FFF,0x7FFF,0x7FFF,0x7FFF,0x7FFF,0x7FFF,0x7FFF,0x7FFF};

    for (int kc = 0; kc < 4; ++kc) {        // K chunks of 128 c
        int c0 = kc << 7;
        __syncthreads();
        /* stage: 512 rows (t,i) x 16 cols j; thread = (row, j-quad) */
#pragma unroll
        for (int sw = 0; sw < 8; ++sw) {
            int r = (sw << 6) + (tid >> 2);
            int t = r >> 7, i = r & 127;
            int j0 = (tid & 3) << 2;
            const float4 v = *reinterpret_cast<const float4*>(
                &x[(((size_t)((t * NN + n) * CIN) + c0 + i) << 10) + hw0 + j0]);
#pragma unroll
            for (int k = 0; k < 4; ++k) {
                float xv = (k == 0) ? v.x : (k == 1) ? v.y : (k == 2) ? v.z : v.w;
                ushort_t a = f2bf(xv);
                ushort_t b = f2bf(xv - bf2f(a));
                int px = ((j0 + k) << 2) + t;
                uint_t off = (((uint_t)px << 8) + ((uint_t)i << 1)) ^ (((uint_t)(px & 7)) << 4);
                *(ushort_t*)((char*)Xa + off) = a;
                *(ushort_t*)((char*)Xb + off) = b;
            }
        }
        __syncthreads();
#pragma unroll
        for (int ks = 0; ks < 4; ++ks) {
            short8 fa[2], fb[2], fm[2];
#pragma unroll
            for (int m = 0; m < 2; ++m) {
                int px = (pxh << 5) + (m << 4) + lr;
                uint_t off = (((uint_t)px << 8) + (uint_t)((ks << 6) + (kq << 4)))
                             ^ (((uint_t)(px & 7)) << 4);
                fa[m] = *(const short8*)((const char*)Xa + off);
                fb[m] = *(const short8*)((const char*)Xb + off);
                fm[m] = fa[m] & MSK;
            }
            int cb = (kc << 4) + (ks << 2) + kq;
#pragma unroll
            for (int ot = 0; ot < 8; ++ot) {
                int o = (oh << 7) + (ot << 4) + lr;
                short8 wa = *(const short8*)(Wa + ((size_t)cb * COUT + o) * 8);
                short8 wb = *(const short8*)(Wb + ((size_t)cb * COUT + o) * 8);
                short8 wm = wa & MSK;
#pragma unroll
                for (int m = 0; m < 2; ++m) {
                    acc[m][ot]  = __builtin_amdgcn_mfma_f32_16x16x32_bf16(fa[m], wa, acc[m][ot], 0, 0, 0);
                    acc[m][ot]  = __builtin_amdgcn_mfma_f32_16x16x32_bf16(fb[m], wa, acc[m][ot], 0, 0, 0);
                    acc[m][ot]  = __builtin_amdgcn_mfma_f32_16x16x32_bf16(fa[m], wb, acc[m][ot], 0, 0, 0);
                    accS[m][ot] = __builtin_amdgcn_mfma_f32_16x16x32_bf16(fm[m], wm, accS[m][ot], 0, 0, 0);
                }
            }
        }
    }

    __syncthreads();
    for (int q = tid; q < 4 * 64 * 8; q += 256) cl[q] = 0;
    __syncthreads();

    double tau = 1.0 / (1.0 + exp(-(double)lif_w[0]));
#pragma unroll
    for (int ot = 0; ot < 8; ++ot) {
        int o = (oh << 7) + (ot << 4) + lr;
        double bi = bias[o];
        uint_t cloc = 0;
#pragma unroll
        for (int m = 0; m < 2; ++m) {
            int hw = hw0 + (pxh << 3) + (m << 2) + kq;
            double v = 0.0;
            bool fl = false;
#pragma unroll
            for (int t = 0; t < 4; ++t) {
                double h = (double)acc[m][ot][t] + bi;
                double eps = 4e-5 * (double)accS[m][ot][t] + 1e-6;
                v += (h - v) * tau;
                if (fabs(v - 1.0) <= 2.0 * eps) fl = true;
                bool s = (v >= 1.0);
                spk[((size_t)((t * NN + n) * HW) + hw) * COUT + o] = s ? (ushort_t)0x3F80 : (ushort_t)0;
                cloc += s ? 1u : 0u;
                if (s) v = 0.0;
            }
            if (fl) {
                uint_t id = atomicAdd(flagcnt, 1u);
                if (id < FLAGCAP) flags[id] = (((uint_t)(n * HW + hw)) << 8) | (uint_t)o;
            }
        }
        cl[(wv << 9) + (lane << 3) + ot] = cloc;
    }
    __syncthreads();
    {
        int o = tid;
        int ohh = o >> 7, ott = (o >> 4) & 7, lr2 = o & 15;
        uint_t s = 0;
#pragma unroll
        for (int w2 = ohh; w2 < 4; w2 += 2)
#pragma unroll
            for (int k2 = 0; k2 < 4; ++k2)
                s += cl[(w2 << 9) + (((k2 << 4) + lr2) << 3) + ott];
        if (s) atomicAdd(&cnt[o], (int)s);
    }
}

/* ---------------- kernel 3b: exact f64 fixup of margin-flagged elements ---------------- */
__global__ __launch_bounds__(256) void k_fixup(
    const float* __restrict__ x, const double* __restrict__ w2t,
    const double* __restrict__ bias, const float* __restrict__ lif_w,
    const uint_t* __restrict__ flags, const uint_t* __restrict__ flagcnt,
    ushort_t* __restrict__ spk, int* __restrict__ cnt)
{
    int nf = (int)*flagcnt; if (nf > FLAGCAP) nf = FLAGCAP;
    int wid = (blockIdx.x << 2) + (threadIdx.x >> 6);
    int lane = threadIdx.x & 63;
    double tau = 1.0 / (1.0 + exp(-(double)lif_w[0]));
    for (int g = wid; g < nf; g += 1024) {
        uint_t f = flags[g];
        int o = f & 255;
        int s = f >> 8;
        int n = s >> 10, hw = s & 1023;
        double h[4];
#pragma unroll
        for (int t = 0; t < 4; ++t) {
            double p = 0.0;
            for (int c = lane; c < CIN; c += 64)
                p += w2t[(size_t)c * COUT + o] *
                     (double)x[(((size_t)((t * NN + n) * CIN) + c) << 10) + hw];
#pragma unroll
            for (int ofs = 32; ofs > 0; ofs >>= 1) p += __shfl_down(p, ofs);
            h[t] = p;
        }
        if (lane == 0) {
            double bi = bias[o];
            double v = 0.0; int delta = 0;
#pragma unroll
            for (int t = 0; t < 4; ++t) {
                v += (h[t] + bi - v) * tau;
                bool sn = (v >= 1.0);
                size_t idx = ((size_t)((t * NN + n) * HW) + hw) * COUT + o;
                ushort_t old = spk[idx];
                ushort_t nw = sn ? (ushort_t)0x3F80 : (ushort_t)0;
                if (old != nw) { spk[idx] = nw; delta += sn ? 1 : -1; }
                if (sn) v = 0.0;
            }
            if (delta) atomicAdd(&cnt[o], delta);
        }
    }
}

/* ---------------- kernel 4pre: BN2 affine from spike counts ---------------- */
__global__ void k_bn2_prep(const int* __restrict__ cnt,
                           const float* __restrict__ gamma2,
                           const float* __restrict__ beta2,
                           double* __restrict__ a2, double* __restrict__ b2) {
    int c = threadIdx.x;
    double n = (double)(FR * 67 * 67);
    double m = (double)cnt[c] / n;
    double var = m - m * m;
    double a = (double)gamma2[c] / sqrt(var + BN_EPS);
    a2[c] = a;
    b2[c] = (double)beta2[c] - m * a;
}

/* ---------------- kernel 4a: bf16 weight table, blocked [ij][c>>3][o][c&7] ---------------- */
__global__ __launch_bounds__(256) void k_wt_prep(const float* __restrict__ up_w,
                                                 const double* __restrict__ a2,
                                                 ushort_t* __restrict__ Wt) {
    int c = blockIdx.x, o = threadIdx.x;
    double a = a2[c];
    const float* u = up_w + ((size_t)c * COUT + o) * 16;
#pragma unroll
    for (int ij = 0; ij < 16; ++ij) {
        float w = (float)(a * (double)u[ij]);
        Wt[(((size_t)ij << 5) + (c >> 3)) * (COUT * 8) + (size_t)o * 8 + (c & 7)] = f2bf(w);
    }
}

/* ---------------- kernel 4b: uniform constant K[o] ---------------- */
__global__ void k_kconst(const float* __restrict__ up_w,
                         const double* __restrict__ b2,
                         float* __restrict__ kc) {
    int o = threadIdx.x;
    double s = 0.0;
    for (int c = 0; c < COUT; ++c) {
        const float* u = up_w + ((size_t)c * COUT + o) * 16;
        double t = 0.0;
#pragma unroll
        for (int k = 0; k < 16; ++k) t += (double)u[k];
        s += b2[c] * t;
    }
    kc[o] = (float)s;
}

/* ---------------- kernel 5: MFMA implicit-GEMM transposed conv ---------------- */
__global__ __launch_bounds__(512) void k_deconv_mfma(const ushort_t* __restrict__ spk,
                                                     const ushort_t* __restrict__ Wt,
                                                     const float* __restrict__ kc,
                                                     float* __restrict__ out) {
    int blk = blockIdx.x;
    int b  = blk >> 5;
    int py = (blk >> 4) & 1;
    int Yb = (blk & 15) << 1;
    int tid = threadIdx.x;
    int wv  = tid >> 6;
    int lane = tid & 63;
    int px = wv >> 2;
    int og = wv & 3;
    int lr = lane & 15;
    int kq = lane >> 4;

    __shared__ ushort_t slab[3 * 34 * 256];     // 52224 B, XOR-swizzled

    int sb = Yb - 1 + py;
    for (int q = tid; q < 3 * 34 * 32; q += 512) {
        int pix = q >> 5;
        int l = q & 31;
        int r = pix / 34;
        int xc = pix - r * 34;
        int sy = sb + r;
        int sx = xc - 1;
        uint_t off = ((uint_t)(pix << 9) + (uint_t)(l << 4)) ^ ((uint_t)(xc & 7) << 4);
        uint4* dst = (uint4*)((char*)slab + off);
        if (sy >= 0 && sy < 32 && sx >= 0 && sx < 32) {
            *dst = *(const uint4*)(spk + ((size_t)b * HW + sy * 32 + sx) * COUT + l * 8);
        } else {
            *dst = make_uint4(0u, 0u, 0u, 0u);
        }
    }
    __syncthreads();

    f32x4 acc[4][4];
#pragma unroll
    for (int pf = 0; pf < 4; ++pf)
#pragma unroll
        for (int of = 0; of < 4; ++of)
            acc[pf][of] = (f32x4){0.f, 0.f, 0.f, 0.f};

    int obase = og << 6;

#pragma unroll
    for (int dy = 0; dy < 2; ++dy) {
#pragma unroll
        for (int dx = 0; dx < 2; ++dx) {
            int i = 3 - py - 2 * dy;
            int j = 3 - px - 2 * dx;
            const ushort_t* wpij = Wt + ((size_t)(i * 4 + j) << 16);
            uint_t sbase[4], swz[4];
#pragma unroll
            for (int pf = 0; pf < 4; ++pf) {
                int pid = pf * 16 + lr;
                int Yq = pid >> 5;
                int X  = pid & 31;
                int xc = X + dx + px;
                int prow = (Yq + dy) * 34 + xc;
                sbase[pf] = ((uint_t)prow << 9) + ((uint_t)kq << 4);
                swz[pf]   = ((uint_t)(xc & 7)) << 4;
            }
#pragma unroll
            for (int cs = 0; cs < 8; ++cs) {
                short8 aw[4];
#pragma unroll
                for (int of = 0; of < 4; ++of)
                    aw[of] = *(const short8*)(wpij +
                        ((size_t)((cs << 2) + kq) * COUT + obase + (of << 4) + lr) * 8);
                short8 bs[4];
#pragma unroll
                for (int pf = 0; pf < 4; ++pf)
                    bs[pf] = *(const short8*)((const char*)slab +
                              ((sbase[pf] + ((uint_t)cs << 6)) ^ swz[pf]));
#pragma unroll
                for (int pf = 0; pf < 4; ++pf)
#pragma unroll
                    for (int of = 0; of < 4; ++of)
                        acc[pf][of] = __builtin_amdgcn_mfma_f32_16x16x32_bf16(
                            aw[of], bs[pf], acc[pf][of], 0, 0, 0);
            }
        }
    }

#pragma unroll
    for (int of = 0; of < 4; ++of) {
#pragma unroll
        for (int rg = 0; rg < 4; ++rg) {
            int o = obase + of * 16 + kq * 4 + rg;
            float base = kc[o];
#pragma unroll
            for (int pf = 0; pf < 4; ++pf) {
                int pid = pf * 16 + lr;
                int Yq = pid >> 5;
                int X  = pid & 31;
                int y = ((Yb + Yq) << 1) + py;
                int x = (X << 1) + px;
                out[((size_t)(b * COUT + o) << 12) + (y << 6) + x] = acc[pf][of][rg] + base;
            }
        }
    }
}

/* ---------------- host launcher ---------------- */
extern "C" void kernel_launch(void* const* d_in, const int* in_sizes, int n_in,
                              void* d_out, int out_size, void* d_ws, size_t ws_size,
                              hipStream_t stream) {
    (void)in_sizes; (void)n_in; (void)out_size; (void)ws_size;
    const float* x        = (const float*)d_in[0];
    const float* bn1_g    = (const float*)d_in[1];
    const float* bn1_b    = (const float*)d_in[2];
    const float* conv_w   = (const float*)d_in[3];
    const float* lif_w    = (const float*)d_in[4];
    const float* bn2_g    = (const float*)d_in[5];
    const float* bn2_b    = (const float*)d_in[6];
    const float* up_w     = (const float*)d_in[7];
    float* out = (float*)d_out;

    char* ws = (char*)d_ws;
    ushort_t* spk  = (ushort_t*)(ws + 0);            // 16 MB (bf16 channel-last)
    double* mean   = (double*)(ws + 16777216);       // 4 KB
    double* alpha  = (double*)(ws + 16781312);       // 4 KB
    double* w2t    = (double*)(ws + 16785408);       // 1 MB
    double* bias   = (double*)(ws + 17833984);       // 2 KB
    double* a2     = (double*)(ws + 17836032);       // 2 KB
    double* b2     = (double*)(ws + 17838080);       // 2 KB
    int*    cnt    = (int*)   (ws + 17840128);       // 1 KB
    float*  kc     = (float*) (ws + 17841152);       // 1 KB
    ushort_t* Wt   = (ushort_t*)(ws + 17842176);     // 2 MB
    ushort_t* Wa   = (ushort_t*)(ws + 19939328);     // 256 KB
    ushort_t* Wb   = (ushort_t*)(ws + 20201472);     // 256 KB
    uint_t* flagcnt= (uint_t*)(ws + 20463616);       // 4 KB
    uint_t* flags  = (uint_t*)(ws + 20467712);       // 4 MB

    hipMemsetAsync(cnt, 0, COUT * sizeof(int), stream);
    hipMemsetAsync(flagcnt, 0, sizeof(uint_t), stream);

    k_bn1_stats<<<CIN, 256, 0, stream>>>(x, bn1_g, mean, alpha);
    k_prep_wsplit<<<COUT, 256, 0, stream>>>(conv_w, alpha, w2t, Wa, Wb);
    k_fold_bias<<<1, COUT, 0, stream>>>(conv_w, bn1_b, mean, alpha, bias);
    k_gemm_lif_mfma<<<512, 256, 0, stream>>>(x, Wa, Wb, bias, lif_w, spk, cnt, flags, flagcnt);
    k_fixup<<<256, 256, 0, stream>>>(x, w2t, bias, lif_w, flags, flagcnt, spk, cnt);
    k_bn2_prep<<<1, COUT, 0, stream>>>(cnt, bn2_g, bn2_b, a2, b2);
    k_wt_prep<<<COUT, COUT, 0, stream>>>(up_w, a2, Wt);
    k_kconst<<<1, COUT, 0, stream>>>(up_w, b2, kc);
    k_deconv_mfma<<<32 * 2 * 16, 512, 0, stream>>>(spk, Wt, kc, out);
}

// Round 4
// 538.952 us; speedup vs baseline: 2.9454x; 1.0217x over previous
//
#include <hip/hip_runtime.h>
#include <math.h>

#define CIN 512
#define COUT 256
#define TT 4
#define NN 8
#define HH 32
#define WW 32
#define FR (TT*NN)   /* 32 frames */
#define HW (HH*WW)   /* 1024 */
#define BN_EPS 1e-5
#define FLAGCAP (1<<20)

typedef unsigned short ushort_t;
typedef unsigned int uint_t;
typedef __attribute__((ext_vector_type(8))) short short8;
typedef __attribute__((ext_vector_type(4))) float f32x4;

__device__ inline ushort_t f2bf(float f) {
    uint_t u = __float_as_uint(f);
    uint_t r = u + 0x7FFFu + ((u >> 16) & 1u);
    return (ushort_t)(r >> 16);
}
__device__ inline float bf2f(ushort_t a) { return __uint_as_float(((uint_t)a) << 16); }

/* ---------------- kernel 1: BN1 per-channel stats (f64) ---------------- */
__global__ __launch_bounds__(256) void k_bn1_stats(const float* __restrict__ x,
                                                   const float* __restrict__ gamma1,
                                                   double* __restrict__ mean,
                                                   double* __restrict__ alpha) {
    int c = blockIdx.x;
    int tid = threadIdx.x;
    double s1 = 0.0, s2 = 0.0;
    const float4* x4 = reinterpret_cast<const float4*>(x);
    for (int f = 0; f < FR; ++f) {
        size_t base4 = ((size_t)(f * CIN + c) * HW) >> 2;
        float4 v = x4[base4 + tid];
        s1 += (double)v.x + (double)v.y + (double)v.z + (double)v.w;
        s2 += (double)v.x * v.x + (double)v.y * v.y + (double)v.z * v.z + (double)v.w * v.w;
    }
    __shared__ double l1[256], l2[256];
    l1[tid] = s1; l2[tid] = s2;
    __syncthreads();
    for (int ofs = 128; ofs > 0; ofs >>= 1) {
        if (tid < ofs) { l1[tid] += l1[tid + ofs]; l2[tid] += l2[tid + ofs]; }
        __syncthreads();
    }
    if (tid == 0) {
        double n = (double)(FR * HW);
        double m = l1[0] / n;
        double var = l2[0] / n - m * m;
        mean[c] = m;
        alpha[c] = (double)gamma1[c] / sqrt(var + BN_EPS);
    }
}

/* ---------------- kernel 1b: split x into bf16 hi/lo tables in MFMA layout ----------------
   Xa/Xb element index: ((blk*4 + pg)*64 + cb)*128 + lr*8 + e
   where blk=(n,hwblk), px=j*4+t (pg=px>>4, lr=px&15), c=cb*8+e.
   Also X2[blk*64+px] = sum_c x^2 (for rigorous Cauchy-Schwarz margin). */
__global__ __launch_bounds__(256) void k_xsplit(const float* __restrict__ x,
                                                ushort_t* __restrict__ Xa_g,
                                                ushort_t* __restrict__ Xb_g,
                                                float* __restrict__ X2_g) {
    int blk = blockIdx.x;
    int n = blk >> 6;
    int hw0 = (blk & 63) << 4;
    int tid = threadIdx.x;
    int pg = tid & 3;
    int rr = tid >> 2;

    __shared__ ushort_t La[8192];   // 16 KB: [pg][cbl][lr][e], XOR-swizzled by pg<<5
    __shared__ ushort_t Lb[8192];
    __shared__ float X2s[64];

    float x2loc[16];
#pragma unroll
    for (int q = 0; q < 16; ++q) x2loc[q] = 0.f;
    if (tid < 64) X2s[tid] = 0.f;

    for (int kc = 0; kc < 4; ++kc) {
        int c0 = kc << 7;
        __syncthreads();
#pragma unroll
        for (int sw = 0; sw < 8; ++sw) {
            const int t = sw >> 1;
            int i = ((sw & 1) << 6) + rr;
            const float4 v = *reinterpret_cast<const float4*>(
                &x[(((size_t)((t * NN + n) * CIN) + c0 + i) << 10) + hw0 + (pg << 2)]);
            int cbl = i >> 3, e = i & 7;
#pragma unroll
            for (int k = 0; k < 4; ++k) {
                float xv = (k == 0) ? v.x : (k == 1) ? v.y : (k == 2) ? v.z : v.w;
                ushort_t a = f2bf(xv);
                ushort_t b = f2bf(xv - bf2f(a));
                x2loc[(k << 2) + t] += xv * xv;
                int lrx = (k << 2) + t;
                uint_t u = ((((uint_t)(pg * 16 + cbl)) * 16 + lrx) << 3) + e;
                uint_t byteoff = (u << 1) ^ ((uint_t)pg << 5);
                *(ushort_t*)((char*)La + byteoff) = a;
                *(ushort_t*)((char*)Lb + byteoff) = b;
            }
        }
        __syncthreads();
        for (int q = tid; q < 1024; q += 256) {
            int pg2 = q >> 8;
            uint_t lo = (uint_t)(q & 255) << 4;
            uint_t src = (((uint_t)pg2 << 12) + lo) ^ ((uint_t)pg2 << 5);
            uint4 va = *(uint4*)((char*)La + src);
            uint4 vb = *(uint4*)((char*)Lb + src);
            size_t dst = (((size_t)blk * 4 + pg2) << 13) + ((size_t)kc << 11) + ((size_t)(q & 255) << 3);
            *(uint4*)(Xa_g + dst) = va;
            *(uint4*)(Xb_g + dst) = vb;
        }
    }
    __syncthreads();
#pragma unroll
    for (int k = 0; k < 4; ++k)
#pragma unroll
        for (int t = 0; t < 4; ++t)
            atomicAdd(&X2s[pg * 16 + k * 4 + t], x2loc[(k << 2) + t]);
    __syncthreads();
    if (tid < 64) X2_g[(blk << 6) + tid] = X2s[tid];
}

/* ---------------- kernel 2a: folded weights: f64 + bf16 splits + W2 ---------------- */
__global__ __launch_bounds__(256) void k_prep_wsplit(const float* __restrict__ conv_w,
                                                     const double* __restrict__ alpha,
                                                     double* __restrict__ w2t,
                                                     ushort_t* __restrict__ Wa,
                                                     ushort_t* __restrict__ Wb,
                                                     float* __restrict__ W2) {
    int o = blockIdx.x;
    float s2 = 0.f;
    for (int c = threadIdx.x; c < CIN; c += 256) {
        double w = (double)conv_w[(size_t)o * CIN + c] * alpha[c];
        w2t[(size_t)c * COUT + o] = w;
        float wf = (float)w;
        ushort_t a = f2bf(wf);
        ushort_t b = f2bf(wf - bf2f(a));
        size_t base = ((size_t)(c >> 3) * COUT + o) * 8 + (c & 7);
        Wa[base] = a; Wb[base] = b;
        s2 += wf * wf;
    }
    __shared__ float red[256];
    red[threadIdx.x] = s2;
    __syncthreads();
    for (int ofs = 128; ofs > 0; ofs >>= 1) {
        if (threadIdx.x < ofs) red[threadIdx.x] += red[threadIdx.x + ofs];
        __syncthreads();
    }
    if (threadIdx.x == 0) W2[o] = red[0];
}

/* ---------------- kernel 2b: folded bias[o] (f64) ---------------- */
__global__ void k_fold_bias(const float* __restrict__ conv_w,
                            const float* __restrict__ beta1,
                            const double* __restrict__ mean,
                            const double* __restrict__ alpha,
                            double* __restrict__ bias) {
    int o = threadIdx.x;
    double s = 0.0;
    for (int c = 0; c < CIN; ++c)
        s += ((double)beta1[c] - mean[c] * alpha[c]) * (double)conv_w[(size_t)o * CIN + c];
    bias[o] = s;
}

/* ---------------- kernel 3: pure-MFMA GEMM + margin + LIF ----------------
   No LDS staging, no barriers in the K loop: fragments come straight from
   global (Xa/Xb pre-laid-out; Wa/Wb L2-resident). 4 waves = (pxh, oh). */
__global__ __launch_bounds__(256) void k_gemm_lif_mfma(
    const ushort_t* __restrict__ Xa_g, const ushort_t* __restrict__ Xb_g,
    const ushort_t* __restrict__ Wa, const ushort_t* __restrict__ Wb,
    const float* __restrict__ X2_g, const float* __restrict__ W2,
    const double* __restrict__ bias, const float* __restrict__ lif_w,
    ushort_t* __restrict__ spk, int* __restrict__ cnt,
    uint_t* __restrict__ flags, uint_t* __restrict__ flagcnt)
{
    int blk = blockIdx.x;            // 512 blocks = (n, hwblk)
    int n   = blk >> 6;
    int hw0 = (blk & 63) << 4;
    int tid = threadIdx.x;
    int wv = tid >> 6, lane = tid & 63;
    int lr = lane & 15, kq = lane >> 4;
    int pxh = wv >> 1, oh = wv & 1;

    __shared__ uint_t cl[4 * 64 * 8];

    f32x4 acc[2][8];
#pragma unroll
    for (int m = 0; m < 2; ++m)
#pragma unroll
        for (int ot = 0; ot < 8; ++ot) acc[m][ot] = (f32x4){0.f, 0.f, 0.f, 0.f};

    const ushort_t* xa0 = Xa_g + (((size_t)blk) << 15) + ((size_t)pxh << 14) + ((uint_t)lane << 3);
    const ushort_t* xb0 = Xb_g + (((size_t)blk) << 15) + ((size_t)pxh << 14) + ((uint_t)lane << 3);
    const ushort_t* wbase_a = Wa + ((uint_t)kq << 11) + ((uint_t)oh << 10) + ((uint_t)lr << 3);
    const ushort_t* wbase_b = Wb + ((uint_t)kq << 11) + ((uint_t)oh << 10) + ((uint_t)lr << 3);

#pragma unroll 2
    for (int ks = 0; ks < 16; ++ks) {
        short8 fa0 = *(const short8*)(xa0 + (ks << 9));
        short8 fa1 = *(const short8*)(xa0 + 8192 + (ks << 9));
        short8 fb0 = *(const short8*)(xb0 + (ks << 9));
        short8 fb1 = *(const short8*)(xb0 + 8192 + (ks << 9));
        const ushort_t* wpa = wbase_a + (ks << 13);
        const ushort_t* wpb = wbase_b + (ks << 13);
#pragma unroll
        for (int ot = 0; ot < 8; ++ot) {
            short8 wa8 = *(const short8*)(wpa + (ot << 7));
            short8 wb8 = *(const short8*)(wpb + (ot << 7));
            acc[0][ot] = __builtin_amdgcn_mfma_f32_16x16x32_bf16(fa0, wa8, acc[0][ot], 0, 0, 0);
            acc[1][ot] = __builtin_amdgcn_mfma_f32_16x16x32_bf16(fa1, wa8, acc[1][ot], 0, 0, 0);
            acc[0][ot] = __builtin_amdgcn_mfma_f32_16x16x32_bf16(fb0, wa8, acc[0][ot], 0, 0, 0);
            acc[1][ot] = __builtin_amdgcn_mfma_f32_16x16x32_bf16(fb1, wa8, acc[1][ot], 0, 0, 0);
            acc[0][ot] = __builtin_amdgcn_mfma_f32_16x16x32_bf16(fa0, wb8, acc[0][ot], 0, 0, 0);
            acc[1][ot] = __builtin_amdgcn_mfma_f32_16x16x32_bf16(fa1, wb8, acc[1][ot], 0, 0, 0);
        }
    }

    /* margin inputs */
    float xs2[2][4];
#pragma unroll
    for (int m = 0; m < 2; ++m)
#pragma unroll
        for (int t = 0; t < 4; ++t)
            xs2[m][t] = X2_g[(blk << 6) + (((pxh << 1) + m) << 4) + (kq << 2) + t];

    for (int q = tid; q < 4 * 64 * 8; q += 256) cl[q] = 0;
    __syncthreads();

    double tau = 1.0 / (1.0 + exp(-(double)lif_w[0]));
#pragma unroll
    for (int ot = 0; ot < 8; ++ot) {
        int o = (oh << 7) + (ot << 4) + lr;
        double bi = bias[o];
        float w2v = W2[o];
        uint_t cloc = 0;
#pragma unroll
        for (int m = 0; m < 2; ++m) {
            int hw = hw0 + (pxh << 3) + (m << 2) + kq;
            double v = 0.0;
            bool fl = false;
#pragma unroll
            for (int t = 0; t < 4; ++t) {
                double h = (double)acc[m][ot][t] + bi;
                double eps = (double)(4e-5f * sqrtf(w2v * xs2[m][t]) + 1e-6f);
                v += (h - v) * tau;
                if (fabs(v - 1.0) <= 2.0 * eps) fl = true;
                bool s = (v >= 1.0);
                spk[((size_t)((t * NN + n) * HW) + hw) * COUT + o] = s ? (ushort_t)0x3F80 : (ushort_t)0;
                cloc += s ? 1u : 0u;
                if (s) v = 0.0;
            }
            if (fl) {
                uint_t id = atomicAdd(flagcnt, 1u);
                if (id < FLAGCAP) flags[id] = (((uint_t)(n * HW + hw)) << 8) | (uint_t)o;
            }
        }
        cl[(wv << 9) + (lane << 3) + ot] = cloc;
    }
    __syncthreads();
    {
        int o = tid;
        int ohh = o >> 7, ott = (o >> 4) & 7, lr2 = o & 15;
        uint_t s = 0;
#pragma unroll
        for (int w2 = ohh; w2 < 4; w2 += 2)
#pragma unroll
            for (int k2 = 0; k2 < 4; ++k2)
                s += cl[(w2 << 9) + (((k2 << 4) + lr2) << 3) + ott];
        if (s) atomicAdd(&cnt[o], (int)s);
    }
}

/* ---------------- kernel 3b: exact f64 fixup of margin-flagged elements ---------------- */
__global__ __launch_bounds__(256) void k_fixup(
    const float* __restrict__ x, const double* __restrict__ w2t,
    const double* __restrict__ bias, const float* __restrict__ lif_w,
    const uint_t* __restrict__ flags, const uint_t* __restrict__ flagcnt,
    ushort_t* __restrict__ spk, int* __restrict__ cnt)
{
    int nf = (int)*flagcnt; if (nf > FLAGCAP) nf = FLAGCAP;
    int wid = (blockIdx.x << 2) + (threadIdx.x >> 6);
    int lane = threadIdx.x & 63;
    double tau = 1.0 / (1.0 + exp(-(double)lif_w[0]));
    for (int g = wid; g < nf; g += 1024) {
        uint_t f = flags[g];
        int o = f & 255;
        int s = f >> 8;
        int n = s >> 10, hw = s & 1023;
        double h[4];
#pragma unroll
        for (int t = 0; t < 4; ++t) {
            double p = 0.0;
            for (int c = lane; c < CIN; c += 64)
                p += w2t[(size_t)c * COUT + o] *
                     (double)x[(((size_t)((t * NN + n) * CIN) + c) << 10) + hw];
#pragma unroll
            for (int ofs = 32; ofs > 0; ofs >>= 1) p += __shfl_down(p, ofs);
            h[t] = p;
        }
        if (lane == 0) {
            double bi = bias[o];
            double v = 0.0; int delta = 0;
#pragma unroll
            for (int t = 0; t < 4; ++t) {
                v += (h[t] + bi - v) * tau;
                bool sn = (v >= 1.0);
                size_t idx = ((size_t)((t * NN + n) * HW) + hw) * COUT + o;
                ushort_t old = spk[idx];
                ushort_t nw = sn ? (ushort_t)0x3F80 : (ushort_t)0;
                if (old != nw) { spk[idx] = nw; delta += sn ? 1 : -1; }
                if (sn) v = 0.0;
            }
            if (delta) atomicAdd(&cnt[o], delta);
        }
    }
}

/* ---------------- kernel 4pre: BN2 affine from spike counts ---------------- */
__global__ void k_bn2_prep(const int* __restrict__ cnt,
                           const float* __restrict__ gamma2,
                           const float* __restrict__ beta2,
                           double* __restrict__ a2, double* __restrict__ b2) {
    int c = threadIdx.x;
    double n = (double)(FR * 67 * 67);
    double m = (double)cnt[c] / n;
    double var = m - m * m;
    double a = (double)gamma2[c] / sqrt(var + BN_EPS);
    a2[c] = a;
    b2[c] = (double)beta2[c] - m * a;
}

/* ---------------- kernel 4a: bf16 weight table, blocked [ij][c>>3][o][c&7] ---------------- */
__global__ __launch_bounds__(256) void k_wt_prep(const float* __restrict__ up_w,
                                                 const double* __restrict__ a2,
                                                 ushort_t* __restrict__ Wt) {
    int c = blockIdx.x, o = threadIdx.x;
    double a = a2[c];
    const float* u = up_w + ((size_t)c * COUT + o) * 16;
#pragma unroll
    for (int ij = 0; ij < 16; ++ij) {
        float w = (float)(a * (double)u[ij]);
        Wt[(((size_t)ij << 5) + (c >> 3)) * (COUT * 8) + (size_t)o * 8 + (c & 7)] = f2bf(w);
    }
}

/* ---------------- kernel 4b: uniform constant K[o] ---------------- */
__global__ void k_kconst(const float* __restrict__ up_w,
                         const double* __restrict__ b2,
                         float* __restrict__ kc) {
    int o = threadIdx.x;
    double s = 0.0;
    for (int c = 0; c < COUT; ++c) {
        const float* u = up_w + ((size_t)c * COUT + o) * 16;
        double t = 0.0;
#pragma unroll
        for (int k = 0; k < 16; ++k) t += (double)u[k];
        s += b2[c] * t;
    }
    kc[o] = (float)s;
}

/* ---------------- kernel 5: MFMA implicit-GEMM transposed conv ---------------- */
__global__ __launch_bounds__(512) void k_deconv_mfma(const ushort_t* __restrict__ spk,
                                                     const ushort_t* __restrict__ Wt,
                                                     const float* __restrict__ kc,
                                                     float* __restrict__ out) {
    int blk = blockIdx.x;
    int b  = blk >> 5;
    int py = (blk >> 4) & 1;
    int Yb = (blk & 15) << 1;
    int tid = threadIdx.x;
    int wv  = tid >> 6;
    int lane = tid & 63;
    int px = wv >> 2;
    int og = wv & 3;
    int lr = lane & 15;
    int kq = lane >> 4;

    __shared__ ushort_t slab[3 * 34 * 256];     // 52224 B, XOR-swizzled

    int sb = Yb - 1 + py;
    for (int q = tid; q < 3 * 34 * 32; q += 512) {
        int pix = q >> 5;
        int l = q & 31;
        int r = pix / 34;
        int xc = pix - r * 34;
        int sy = sb + r;
        int sx = xc - 1;
        uint_t off = ((uint_t)(pix << 9) + (uint_t)(l << 4)) ^ ((uint_t)(xc & 7) << 4);
        uint4* dst = (uint4*)((char*)slab + off);
        if (sy >= 0 && sy < 32 && sx >= 0 && sx < 32) {
            *dst = *(const uint4*)(spk + ((size_t)b * HW + sy * 32 + sx) * COUT + l * 8);
        } else {
            *dst = make_uint4(0u, 0u, 0u, 0u);
        }
    }
    __syncthreads();

    f32x4 acc[4][4];
#pragma unroll
    for (int pf = 0; pf < 4; ++pf)
#pragma unroll
        for (int of = 0; of < 4; ++of)
            acc[pf][of] = (f32x4){0.f, 0.f, 0.f, 0.f};

    int obase = og << 6;

#pragma unroll
    for (int dy = 0; dy < 2; ++dy) {
#pragma unroll
        for (int dx = 0; dx < 2; ++dx) {
            int i = 3 - py - 2 * dy;
            int j = 3 - px - 2 * dx;
            const ushort_t* wpij = Wt + ((size_t)(i * 4 + j) << 16);
            uint_t sbase[4], swz[4];
#pragma unroll
            for (int pf = 0; pf < 4; ++pf) {
                int pid = pf * 16 + lr;
                int Yq = pid >> 5;
                int X  = pid & 31;
                int xc = X + dx + px;
                int prow = (Yq + dy) * 34 + xc;
                sbase[pf] = ((uint_t)prow << 9) + ((uint_t)kq << 4);
                swz[pf]   = ((uint_t)(xc & 7)) << 4;
            }
#pragma unroll
            for (int cs = 0; cs < 8; ++cs) {
                short8 aw[4];
#pragma unroll
                for (int of = 0; of < 4; ++of)
                    aw[of] = *(const short8*)(wpij +
                        ((size_t)((cs << 2) + kq) * COUT + obase + (of << 4) + lr) * 8);
                short8 bs[4];
#pragma unroll
                for (int pf = 0; pf < 4; ++pf)
                    bs[pf] = *(const short8*)((const char*)slab +
                              ((sbase[pf] + ((uint_t)cs << 6)) ^ swz[pf]));
#pragma unroll
                for (int pf = 0; pf < 4; ++pf)
#pragma unroll
                    for (int of = 0; of < 4; ++of)
                        acc[pf][of] = __builtin_amdgcn_mfma_f32_16x16x32_bf16(
                            aw[of], bs[pf], acc[pf][of], 0, 0, 0);
            }
        }
    }

#pragma unroll
    for (int of = 0; of < 4; ++of) {
#pragma unroll
        for (int rg = 0; rg < 4; ++rg) {
            int o = obase + of * 16 + kq * 4 + rg;
            float base = kc[o];
#pragma unroll
            for (int pf = 0; pf < 4; ++pf) {
                int pid = pf * 16 + lr;
                int Yq = pid >> 5;
                int X  = pid & 31;
                int y = ((Yb + Yq) << 1) + py;
                int x = (X << 1) + px;
                out[((size_t)(b * COUT + o) << 12) + (y << 6) + x] = acc[pf][of][rg] + base;
            }
        }
    }
}

/* ---------------- host launcher ---------------- */
extern "C" void kernel_launch(void* const* d_in, const int* in_sizes, int n_in,
                              void* d_out, int out_size, void* d_ws, size_t ws_size,
                              hipStream_t stream) {
    (void)in_sizes; (void)n_in; (void)out_size; (void)ws_size;
    const float* x        = (const float*)d_in[0];
    const float* bn1_g    = (const float*)d_in[1];
    const float* bn1_b    = (const float*)d_in[2];
    const float* conv_w   = (const float*)d_in[3];
    const float* lif_w    = (const float*)d_in[4];
    const float* bn2_g    = (const float*)d_in[5];
    const float* bn2_b    = (const float*)d_in[6];
    const float* up_w     = (const float*)d_in[7];
    float* out = (float*)d_out;

    char* ws = (char*)d_ws;
    ushort_t* spk  = (ushort_t*)(ws + 0);            // 16 MB
    ushort_t* Xa_g = (ushort_t*)(ws + 16777216);     // 33.5 MB
    ushort_t* Xb_g = (ushort_t*)(ws + 50331648);     // 33.5 MB
    float*  X2_g   = (float*)  (ws + 83886080);      // 128 KB
    float*  W2     = (float*)  (ws + 84017152);      // 1 KB
    double* mean   = (double*) (ws + 84018176);      // 4 KB
    double* alpha  = (double*) (ws + 84022272);      // 4 KB
    double* w2t    = (double*) (ws + 84026368);      // 1 MB
    double* bias   = (double*) (ws + 85074944);      // 2 KB
    double* a2     = (double*) (ws + 85076992);      // 2 KB
    double* b2     = (double*) (ws + 85079040);      // 2 KB
    int*    cnt    = (int*)    (ws + 85081088);      // 1 KB
    float*  kc     = (float*)  (ws + 85082112);      // 1 KB
    ushort_t* Wt   = (ushort_t*)(ws + 85083136);     // 2 MB
    ushort_t* Wa   = (ushort_t*)(ws + 87180288);     // 256 KB
    ushort_t* Wb   = (ushort_t*)(ws + 87442432);     // 256 KB
    uint_t* flagcnt= (uint_t*) (ws + 87704576);      // 1 KB
    uint_t* flags  = (uint_t*) (ws + 87705600);      // 4 MB

    hipMemsetAsync(cnt, 0, COUT * sizeof(int), stream);
    hipMemsetAsync(flagcnt, 0, sizeof(uint_t), stream);

    k_bn1_stats<<<CIN, 256, 0, stream>>>(x, bn1_g, mean, alpha);
    k_xsplit<<<512, 256, 0, stream>>>(x, Xa_g, Xb_g, X2_g);
    k_prep_wsplit<<<COUT, 256, 0, stream>>>(conv_w, alpha, w2t, Wa, Wb, W2);
    k_fold_bias<<<1, COUT, 0, stream>>>(conv_w, bn1_b, mean, alpha, bias);
    k_gemm_lif_mfma<<<512, 256, 0, stream>>>(Xa_g, Xb_g, Wa, Wb, X2_g, W2,
                                             bias, lif_w, spk, cnt, flags, flagcnt);
    k_fixup<<<256, 256, 0, stream>>>(x, w2t, bias, lif_w, flags, flagcnt, spk, cnt);
    k_bn2_prep<<<1, COUT, 0, stream>>>(cnt, bn2_g, bn2_b, a2, b2);
    k_wt_prep<<<COUT, COUT, 0, stream>>>(up_w, a2, Wt);
    k_kconst<<<1, COUT, 0, stream>>>(up_w, b2, kc);
    k_deconv_mfma<<<32 * 2 * 16, 512, 0, stream>>>(spk, Wt, kc, out);
}

// Round 5
// 414.112 us; speedup vs baseline: 3.8334x; 1.3015x over previous
//
#include <hip/hip_runtime.h>
#include <math.h>

#define CIN 512
#define COUT 256
#define TT 4
#define NN 8
#define HH 32
#define WW 32
#define FR (TT*NN)   /* 32 frames */
#define HW (HH*WW)   /* 1024 */
#define BN_EPS 1e-5
#define FLAGCAP (1<<20)

typedef unsigned short ushort_t;
typedef unsigned int uint_t;
typedef __attribute__((ext_vector_type(8))) short short8;
typedef __attribute__((ext_vector_type(4))) float f32x4;

__device__ inline ushort_t f2bf(float f) {
    uint_t u = __float_as_uint(f);
    uint_t r = u + 0x7FFFu + ((u >> 16) & 1u);
    return (ushort_t)(r >> 16);
}
__device__ inline float bf2f(ushort_t a) { return __uint_as_float(((uint_t)a) << 16); }

/* ---------------- kernel 1: BN1 per-channel stats (f64) ---------------- */
__global__ __launch_bounds__(256) void k_bn1_stats(const float* __restrict__ x,
                                                   const float* __restrict__ gamma1,
                                                   double* __restrict__ mean,
                                                   double* __restrict__ alpha) {
    int c = blockIdx.x;
    int tid = threadIdx.x;
    double s1 = 0.0, s2 = 0.0;
    const float4* x4 = reinterpret_cast<const float4*>(x);
    for (int f = 0; f < FR; ++f) {
        size_t base4 = ((size_t)(f * CIN + c) * HW) >> 2;
        float4 v = x4[base4 + tid];
        s1 += (double)v.x + (double)v.y + (double)v.z + (double)v.w;
        s2 += (double)v.x * v.x + (double)v.y * v.y + (double)v.z * v.z + (double)v.w * v.w;
    }
    __shared__ double l1[256], l2[256];
    l1[tid] = s1; l2[tid] = s2;
    __syncthreads();
    for (int ofs = 128; ofs > 0; ofs >>= 1) {
        if (tid < ofs) { l1[tid] += l1[tid + ofs]; l2[tid] += l2[tid + ofs]; }
        __syncthreads();
    }
    if (tid == 0) {
        double n = (double)(FR * HW);
        double m = l1[0] / n;
        double var = l2[0] / n - m * m;
        mean[c] = m;
        alpha[c] = (double)gamma1[c] / sqrt(var + BN_EPS);
    }
}

/* ---------------- kernel 1b: split x into bf16 hi/lo tables in MFMA layout ---------------- */
__global__ __launch_bounds__(256) void k_xsplit(const float* __restrict__ x,
                                                ushort_t* __restrict__ Xa_g,
                                                ushort_t* __restrict__ Xb_g,
                                                float* __restrict__ X2_g) {
    int blk = blockIdx.x;
    int n = blk >> 6;
    int hw0 = (blk & 63) << 4;
    int tid = threadIdx.x;
    int pg = tid & 3;
    int rr = tid >> 2;

    __shared__ ushort_t La[8192];
    __shared__ ushort_t Lb[8192];
    __shared__ float X2s[64];

    float x2loc[16];
#pragma unroll
    for (int q = 0; q < 16; ++q) x2loc[q] = 0.f;
    if (tid < 64) X2s[tid] = 0.f;

    for (int kc = 0; kc < 4; ++kc) {
        int c0 = kc << 7;
        __syncthreads();
#pragma unroll
        for (int sw = 0; sw < 8; ++sw) {
            const int t = sw >> 1;
            int i = ((sw & 1) << 6) + rr;
            const float4 v = *reinterpret_cast<const float4*>(
                &x[(((size_t)((t * NN + n) * CIN) + c0 + i) << 10) + hw0 + (pg << 2)]);
            int cbl = i >> 3, e = i & 7;
#pragma unroll
            for (int k = 0; k < 4; ++k) {
                float xv = (k == 0) ? v.x : (k == 1) ? v.y : (k == 2) ? v.z : v.w;
                ushort_t a = f2bf(xv);
                ushort_t b = f2bf(xv - bf2f(a));
                x2loc[(k << 2) + t] += xv * xv;
                int lrx = (k << 2) + t;
                uint_t u = ((((uint_t)(pg * 16 + cbl)) * 16 + lrx) << 3) + e;
                uint_t byteoff = (u << 1) ^ ((uint_t)pg << 5);
                *(ushort_t*)((char*)La + byteoff) = a;
                *(ushort_t*)((char*)Lb + byteoff) = b;
            }
        }
        __syncthreads();
        for (int q = tid; q < 1024; q += 256) {
            int pg2 = q >> 8;
            uint_t lo = (uint_t)(q & 255) << 4;
            uint_t src = (((uint_t)pg2 << 12) + lo) ^ ((uint_t)pg2 << 5);
            uint4 va = *(uint4*)((char*)La + src);
            uint4 vb = *(uint4*)((char*)Lb + src);
            size_t dst = (((size_t)blk * 4 + pg2) << 13) + ((size_t)kc << 11) + ((size_t)(q & 255) << 3);
            *(uint4*)(Xa_g + dst) = va;
            *(uint4*)(Xb_g + dst) = vb;
        }
    }
    __syncthreads();
#pragma unroll
    for (int k = 0; k < 4; ++k)
#pragma unroll
        for (int t = 0; t < 4; ++t)
            atomicAdd(&X2s[pg * 16 + k * 4 + t], x2loc[(k << 2) + t]);
    __syncthreads();
    if (tid < 64) X2_g[(blk << 6) + tid] = X2s[tid];
}

/* ---------------- kernel 2a: folded weights: f64 + bf16 splits + W2 ---------------- */
__global__ __launch_bounds__(256) void k_prep_wsplit(const float* __restrict__ conv_w,
                                                     const double* __restrict__ alpha,
                                                     double* __restrict__ w2t,
                                                     ushort_t* __restrict__ Wa,
                                                     ushort_t* __restrict__ Wb,
                                                     float* __restrict__ W2) {
    int o = blockIdx.x;
    float s2 = 0.f;
    for (int c = threadIdx.x; c < CIN; c += 256) {
        double w = (double)conv_w[(size_t)o * CIN + c] * alpha[c];
        w2t[(size_t)c * COUT + o] = w;
        float wf = (float)w;
        ushort_t a = f2bf(wf);
        ushort_t b = f2bf(wf - bf2f(a));
        size_t base = ((size_t)(c >> 3) * COUT + o) * 8 + (c & 7);
        Wa[base] = a; Wb[base] = b;
        s2 += wf * wf;
    }
    __shared__ float red[256];
    red[threadIdx.x] = s2;
    __syncthreads();
    for (int ofs = 128; ofs > 0; ofs >>= 1) {
        if (threadIdx.x < ofs) red[threadIdx.x] += red[threadIdx.x + ofs];
        __syncthreads();
    }
    if (threadIdx.x == 0) W2[o] = red[0];
}

/* ---------------- kernel 2b: folded bias[o] (f64), parallel over o ---------------- */
__global__ __launch_bounds__(256) void k_fold_bias(const float* __restrict__ conv_w,
                                                   const float* __restrict__ beta1,
                                                   const double* __restrict__ mean,
                                                   const double* __restrict__ alpha,
                                                   double* __restrict__ bias) {
    int o = blockIdx.x;
    int c = threadIdx.x;
    double s = ((double)beta1[c] - mean[c] * alpha[c]) * (double)conv_w[(size_t)o * CIN + c]
             + ((double)beta1[c + 256] - mean[c + 256] * alpha[c + 256]) *
               (double)conv_w[(size_t)o * CIN + c + 256];
    __shared__ double red[256];
    red[c] = s;
    __syncthreads();
    for (int ofs = 128; ofs > 0; ofs >>= 1) {
        if (c < ofs) red[c] += red[c + ofs];
        __syncthreads();
    }
    if (c == 0) bias[o] = red[0];
}

/* ---------------- kernel 3: pure-MFMA GEMM + margin + LIF ---------------- */
__global__ __launch_bounds__(256) void k_gemm_lif_mfma(
    const ushort_t* __restrict__ Xa_g, const ushort_t* __restrict__ Xb_g,
    const ushort_t* __restrict__ Wa, const ushort_t* __restrict__ Wb,
    const float* __restrict__ X2_g, const float* __restrict__ W2,
    const double* __restrict__ bias, const float* __restrict__ lif_w,
    ushort_t* __restrict__ spk, int* __restrict__ cnt,
    uint_t* __restrict__ flags, uint_t* __restrict__ flagcnt)
{
    int blk = blockIdx.x;
    int n   = blk >> 6;
    int hw0 = (blk & 63) << 4;
    int tid = threadIdx.x;
    int wv = tid >> 6, lane = tid & 63;
    int lr = lane & 15, kq = lane >> 4;
    int pxh = wv >> 1, oh = wv & 1;

    __shared__ uint_t cl[4 * 64 * 8];

    f32x4 acc[2][8];
#pragma unroll
    for (int m = 0; m < 2; ++m)
#pragma unroll
        for (int ot = 0; ot < 8; ++ot) acc[m][ot] = (f32x4){0.f, 0.f, 0.f, 0.f};

    const ushort_t* xa0 = Xa_g + (((size_t)blk) << 15) + ((size_t)pxh << 14) + ((uint_t)lane << 3);
    const ushort_t* xb0 = Xb_g + (((size_t)blk) << 15) + ((size_t)pxh << 14) + ((uint_t)lane << 3);
    const ushort_t* wbase_a = Wa + ((uint_t)kq << 11) + ((uint_t)oh << 10) + ((uint_t)lr << 3);
    const ushort_t* wbase_b = Wb + ((uint_t)kq << 11) + ((uint_t)oh << 10) + ((uint_t)lr << 3);

#pragma unroll 2
    for (int ks = 0; ks < 16; ++ks) {
        short8 fa0 = *(const short8*)(xa0 + (ks << 9));
        short8 fa1 = *(const short8*)(xa0 + 8192 + (ks << 9));
        short8 fb0 = *(const short8*)(xb0 + (ks << 9));
        short8 fb1 = *(const short8*)(xb0 + 8192 + (ks << 9));
        const ushort_t* wpa = wbase_a + (ks << 13);
        const ushort_t* wpb = wbase_b + (ks << 13);
#pragma unroll
        for (int ot = 0; ot < 8; ++ot) {
            short8 wa8 = *(const short8*)(wpa + (ot << 7));
            short8 wb8 = *(const short8*)(wpb + (ot << 7));
            acc[0][ot] = __builtin_amdgcn_mfma_f32_16x16x32_bf16(fa0, wa8, acc[0][ot], 0, 0, 0);
            acc[1][ot] = __builtin_amdgcn_mfma_f32_16x16x32_bf16(fa1, wa8, acc[1][ot], 0, 0, 0);
            acc[0][ot] = __builtin_amdgcn_mfma_f32_16x16x32_bf16(fb0, wa8, acc[0][ot], 0, 0, 0);
            acc[1][ot] = __builtin_amdgcn_mfma_f32_16x16x32_bf16(fb1, wa8, acc[1][ot], 0, 0, 0);
            acc[0][ot] = __builtin_amdgcn_mfma_f32_16x16x32_bf16(fa0, wb8, acc[0][ot], 0, 0, 0);
            acc[1][ot] = __builtin_amdgcn_mfma_f32_16x16x32_bf16(fa1, wb8, acc[1][ot], 0, 0, 0);
        }
    }

    float xs2[2][4];
#pragma unroll
    for (int m = 0; m < 2; ++m)
#pragma unroll
        for (int t = 0; t < 4; ++t)
            xs2[m][t] = X2_g[(blk << 6) + (((pxh << 1) + m) << 4) + (kq << 2) + t];

    for (int q = tid; q < 4 * 64 * 8; q += 256) cl[q] = 0;
    __syncthreads();

    double tau = 1.0 / (1.0 + exp(-(double)lif_w[0]));
#pragma unroll
    for (int ot = 0; ot < 8; ++ot) {
        int o = (oh << 7) + (ot << 4) + lr;
        double bi = bias[o];
        float w2v = W2[o];
        uint_t cloc = 0;
#pragma unroll
        for (int m = 0; m < 2; ++m) {
            int hw = hw0 + (pxh << 3) + (m << 2) + kq;
            double v = 0.0;
            bool fl = false;
#pragma unroll
            for (int t = 0; t < 4; ++t) {
                double h = (double)acc[m][ot][t] + bi;
                double eps = (double)(4e-5f * sqrtf(w2v * xs2[m][t]) + 1e-6f);
                v += (h - v) * tau;
                if (fabs(v - 1.0) <= 2.0 * eps) fl = true;
                bool s = (v >= 1.0);
                spk[((size_t)((t * NN + n) * HW) + hw) * COUT + o] = s ? (ushort_t)0x3F80 : (ushort_t)0;
                cloc += s ? 1u : 0u;
                if (s) v = 0.0;
            }
            if (fl) {
                uint_t id = atomicAdd(flagcnt, 1u);
                if (id < FLAGCAP) flags[id] = (((uint_t)(n * HW + hw)) << 8) | (uint_t)o;
            }
        }
        cl[(wv << 9) + (lane << 3) + ot] = cloc;
    }
    __syncthreads();
    {
        int o = tid;
        int ohh = o >> 7, ott = (o >> 4) & 7, lr2 = o & 15;
        uint_t s = 0;
#pragma unroll
        for (int w2 = ohh; w2 < 4; w2 += 2)
#pragma unroll
            for (int k2 = 0; k2 < 4; ++k2)
                s += cl[(w2 << 9) + (((k2 << 4) + lr2) << 3) + ott];
        if (s) atomicAdd(&cnt[o], (int)s);
    }
}

/* ---------------- kernel 3b: exact f64 fixup of margin-flagged elements ---------------- */
__global__ __launch_bounds__(256) void k_fixup(
    const float* __restrict__ x, const double* __restrict__ w2t,
    const double* __restrict__ bias, const float* __restrict__ lif_w,
    const uint_t* __restrict__ flags, const uint_t* __restrict__ flagcnt,
    ushort_t* __restrict__ spk, int* __restrict__ cnt)
{
    int nf = (int)*flagcnt; if (nf > FLAGCAP) nf = FLAGCAP;
    int wid = (blockIdx.x << 2) + (threadIdx.x >> 6);
    int lane = threadIdx.x & 63;
    double tau = 1.0 / (1.0 + exp(-(double)lif_w[0]));
    for (int g = wid; g < nf; g += 1024) {
        uint_t f = flags[g];
        int o = f & 255;
        int s = f >> 8;
        int n = s >> 10, hw = s & 1023;
        double h[4];
#pragma unroll
        for (int t = 0; t < 4; ++t) {
            double p = 0.0;
            for (int c = lane; c < CIN; c += 64)
                p += w2t[(size_t)c * COUT + o] *
                     (double)x[(((size_t)((t * NN + n) * CIN) + c) << 10) + hw];
#pragma unroll
            for (int ofs = 32; ofs > 0; ofs >>= 1) p += __shfl_down(p, ofs);
            h[t] = p;
        }
        if (lane == 0) {
            double bi = bias[o];
            double v = 0.0; int delta = 0;
#pragma unroll
            for (int t = 0; t < 4; ++t) {
                v += (h[t] + bi - v) * tau;
                bool sn = (v >= 1.0);
                size_t idx = ((size_t)((t * NN + n) * HW) + hw) * COUT + o;
                ushort_t old = spk[idx];
                ushort_t nw = sn ? (ushort_t)0x3F80 : (ushort_t)0;
                if (old != nw) { spk[idx] = nw; delta += sn ? 1 : -1; }
                if (sn) v = 0.0;
            }
            if (delta) atomicAdd(&cnt[o], delta);
        }
    }
}

/* ---------------- kernel 4pre: BN2 affine from spike counts ---------------- */
__global__ void k_bn2_prep(const int* __restrict__ cnt,
                           const float* __restrict__ gamma2,
                           const float* __restrict__ beta2,
                           double* __restrict__ a2, double* __restrict__ b2) {
    int c = threadIdx.x;
    double n = (double)(FR * 67 * 67);
    double m = (double)cnt[c] / n;
    double var = m - m * m;
    double a = (double)gamma2[c] / sqrt(var + BN_EPS);
    a2[c] = a;
    b2[c] = (double)beta2[c] - m * a;
}

/* ---------------- kernel 4a: bf16 weight table, coalesced writes ----------------
   block = (ij, cb); thread = o; writes 16B contiguous per thread. */
__global__ __launch_bounds__(256) void k_wt_prep(const float* __restrict__ up_w,
                                                 const double* __restrict__ a2,
                                                 ushort_t* __restrict__ Wt) {
    int blk = blockIdx.x;          // 512 = ij*32 + cb
    int ij = blk >> 5, cb = blk & 31;
    int o = threadIdx.x;
    short8 v;
#pragma unroll
    for (int e = 0; e < 8; ++e) {
        int c = (cb << 3) + e;
        float w = (float)(a2[c] * (double)up_w[(((size_t)c * COUT) + o) * 16 + ij]);
        v[e] = (short)f2bf(w);
    }
    *(short8*)(Wt + ((size_t)ij << 16) + ((size_t)cb << 11) + ((size_t)o << 3)) = v;
}

/* ---------------- kernel 4b: uniform constant K[o], parallel over o ---------------- */
__global__ __launch_bounds__(256) void k_kconst(const float* __restrict__ up_w,
                                                const double* __restrict__ b2,
                                                float* __restrict__ kc) {
    int o = blockIdx.x, c = threadIdx.x;
    const float* u = up_w + ((size_t)c * COUT + o) * 16;
    double t = 0.0;
#pragma unroll
    for (int k = 0; k < 16; ++k) t += (double)u[k];
    double s = b2[c] * t;
    __shared__ double red[256];
    red[c] = s;
    __syncthreads();
    for (int ofs = 128; ofs > 0; ofs >>= 1) {
        if (c < ofs) red[c] += red[c + ofs];
        __syncthreads();
    }
    if (c == 0) kc[o] = (float)red[0];
}

/* ---------------- kernel 5: MFMA implicit-GEMM transposed conv ----------------
   XCD-grouped swizzle; LDS-staged coalesced epilogue. */
__global__ __launch_bounds__(512) void k_deconv_mfma(const ushort_t* __restrict__ spk,
                                                     const ushort_t* __restrict__ Wt,
                                                     const float* __restrict__ kc,
                                                     float* __restrict__ out) {
    int p = blockIdx.x;
    int w = ((p & 7) << 7) + (p >> 3);   // frames grouped per-XCD (1024 % 8 == 0)
    int b  = w >> 5;
    int py = (w >> 4) & 1;
    int Yb = (w & 15) << 1;
    int tid = threadIdx.x;
    int wv  = tid >> 6;
    int lane = tid & 63;
    int px = wv >> 2;
    int og = wv & 3;
    int lr = lane & 15;
    int kq = lane >> 4;

    __shared__ __align__(16) char smem[52224];   // slab (52224B) reused as stage (32768B)
    ushort_t* slab = (ushort_t*)smem;

    int sb = Yb - 1 + py;
    for (int q = tid; q < 3 * 34 * 32; q += 512) {
        int pix = q >> 5;
        int l = q & 31;
        int r = pix / 34;
        int xc = pix - r * 34;
        int sy = sb + r;
        int sx = xc - 1;
        uint_t off = ((uint_t)(pix << 9) + (uint_t)(l << 4)) ^ ((uint_t)(xc & 7) << 4);
        uint4* dst = (uint4*)((char*)slab + off);
        if (sy >= 0 && sy < 32 && sx >= 0 && sx < 32) {
            *dst = *(const uint4*)(spk + ((size_t)b * HW + sy * 32 + sx) * COUT + l * 8);
        } else {
            *dst = make_uint4(0u, 0u, 0u, 0u);
        }
    }
    __syncthreads();

    f32x4 acc[4][4];
#pragma unroll
    for (int pf = 0; pf < 4; ++pf)
#pragma unroll
        for (int of = 0; of < 4; ++of)
            acc[pf][of] = (f32x4){0.f, 0.f, 0.f, 0.f};

    int obase = og << 6;

#pragma unroll
    for (int dy = 0; dy < 2; ++dy) {
#pragma unroll
        for (int dx = 0; dx < 2; ++dx) {
            int i = 3 - py - 2 * dy;
            int j = 3 - px - 2 * dx;
            const ushort_t* wpij = Wt + ((size_t)(i * 4 + j) << 16);
            uint_t sbase[4], swz[4];
#pragma unroll
            for (int pf = 0; pf < 4; ++pf) {
                int pid = pf * 16 + lr;
                int Yq = pid >> 5;
                int X  = pid & 31;
                int xc = X + dx + px;
                int prow = (Yq + dy) * 34 + xc;
                sbase[pf] = ((uint_t)prow << 9) + ((uint_t)kq << 4);
                swz[pf]   = ((uint_t)(xc & 7)) << 4;
            }
#pragma unroll
            for (int cs = 0; cs < 8; ++cs) {
                short8 aw[4];
#pragma unroll
                for (int of = 0; of < 4; ++of)
                    aw[of] = *(const short8*)(wpij +
                        ((size_t)((cs << 2) + kq) * COUT + obase + (of << 4) + lr) * 8);
                short8 bs[4];
#pragma unroll
                for (int pf = 0; pf < 4; ++pf)
                    bs[pf] = *(const short8*)((const char*)slab +
                              ((sbase[pf] + ((uint_t)cs << 6)) ^ swz[pf]));
#pragma unroll
                for (int pf = 0; pf < 4; ++pf)
#pragma unroll
                    for (int of = 0; of < 4; ++of)
                        acc[pf][of] = __builtin_amdgcn_mfma_f32_16x16x32_bf16(
                            aw[of], bs[pf], acc[pf][of], 0, 0, 0);
            }
        }
    }

    /* ---- LDS-staged coalesced epilogue: 4 rounds of 64 o x 2 y x 64 x ---- */
    __syncthreads();                 // all slab reads done; reuse smem
    float* stage = (float*)smem;
#pragma unroll 1
    for (int of = 0; of < 4; ++of) {
        if (of) __syncthreads();
#pragma unroll
        for (int rg = 0; rg < 4; ++rg) {
            int row = (og << 4) + (kq << 2) + rg;
#pragma unroll
            for (int pf = 0; pf < 4; ++pf) {
                int Yq = pf >> 1;
                int x = ((((pf & 1) << 4) + lr) << 1) + px;
                uint_t a4 = ((uint_t)row << 5) + ((uint_t)Yq << 4)
                          + (((uint_t)x >> 2) ^ ((uint_t)kq << 2));
                stage[(a4 << 2) + (x & 3)] = acc[pf][of][rg];
            }
        }
        __syncthreads();
#pragma unroll
        for (int rep = 0; rep < 4; ++rep) {
            int u = tid + (rep << 9);
            int r = u >> 5, rem = u & 31;
            int yq = rem >> 4, f4 = rem & 15;
            uint_t a4 = ((uint_t)r << 5) + ((uint_t)yq << 4)
                      + ((uint_t)f4 ^ ((((uint_t)r >> 2) & 3) << 2));
            float4 v = ((const float4*)stage)[a4];
            int o = ((r >> 4) << 6) + (of << 4) + (r & 15);
            float base = kc[o];
            v.x += base; v.y += base; v.z += base; v.w += base;
            int y = ((Yb + yq) << 1) + py;
            *(float4*)(out + ((size_t)(b * COUT + o) << 12) + (y << 6) + (f4 << 2)) = v;
        }
    }
}

/* ---------------- host launcher ---------------- */
extern "C" void kernel_launch(void* const* d_in, const int* in_sizes, int n_in,
                              void* d_out, int out_size, void* d_ws, size_t ws_size,
                              hipStream_t stream) {
    (void)in_sizes; (void)n_in; (void)out_size; (void)ws_size;
    const float* x        = (const float*)d_in[0];
    const float* bn1_g    = (const float*)d_in[1];
    const float* bn1_b    = (const float*)d_in[2];
    const float* conv_w   = (const float*)d_in[3];
    const float* lif_w    = (const float*)d_in[4];
    const float* bn2_g    = (const float*)d_in[5];
    const float* bn2_b    = (const float*)d_in[6];
    const float* up_w     = (const float*)d_in[7];
    float* out = (float*)d_out;

    char* ws = (char*)d_ws;
    ushort_t* spk  = (ushort_t*)(ws + 0);            // 16 MB
    ushort_t* Xa_g = (ushort_t*)(ws + 16777216);     // 33.5 MB
    ushort_t* Xb_g = (ushort_t*)(ws + 50331648);     // 33.5 MB
    float*  X2_g   = (float*)  (ws + 83886080);      // 128 KB
    float*  W2     = (float*)  (ws + 84017152);      // 1 KB
    double* mean   = (double*) (ws + 84018176);      // 4 KB
    double* alpha  = (double*) (ws + 84022272);      // 4 KB
    double* w2t    = (double*) (ws + 84026368);      // 1 MB
    double* bias   = (double*) (ws + 85074944);      // 2 KB
    double* a2     = (double*) (ws + 85076992);      // 2 KB
    double* b2     = (double*) (ws + 85079040);      // 2 KB
    int*    cnt    = (int*)    (ws + 85081088);      // 1 KB
    float*  kc     = (float*)  (ws + 85082112);      // 1 KB
    ushort_t* Wt   = (ushort_t*)(ws + 85083136);     // 2 MB
    ushort_t* Wa   = (ushort_t*)(ws + 87180288);     // 256 KB
    ushort_t* Wb   = (ushort_t*)(ws + 87442432);     // 256 KB
    uint_t* flagcnt= (uint_t*) (ws + 87704576);      // 1 KB
    uint_t* flags  = (uint_t*) (ws + 87705600);      // 4 MB

    hipMemsetAsync(cnt, 0, COUT * sizeof(int), stream);
    hipMemsetAsync(flagcnt, 0, sizeof(uint_t), stream);

    k_bn1_stats<<<CIN, 256, 0, stream>>>(x, bn1_g, mean, alpha);
    k_xsplit<<<512, 256, 0, stream>>>(x, Xa_g, Xb_g, X2_g);
    k_prep_wsplit<<<COUT, 256, 0, stream>>>(conv_w, alpha, w2t, Wa, Wb, W2);
    k_fold_bias<<<COUT, 256, 0, stream>>>(conv_w, bn1_b, mean, alpha, bias);
    k_gemm_lif_mfma<<<512, 256, 0, stream>>>(Xa_g, Xb_g, Wa, Wb, X2_g, W2,
                                             bias, lif_w, spk, cnt, flags, flagcnt);
    k_fixup<<<256, 256, 0, stream>>>(x, w2t, bias, lif_w, flags, flagcnt, spk, cnt);
    k_bn2_prep<<<1, COUT, 0, stream>>>(cnt, bn2_g, bn2_b, a2, b2);
    k_wt_prep<<<512, 256, 0, stream>>>(up_w, a2, Wt);
    k_kconst<<<COUT, 256, 0, stream>>>(up_w, b2, kc);
    k_deconv_mfma<<<32 * 2 * 16, 512, 0, stream>>>(spk, Wt, kc, out);
}